// Round 6
// baseline (184.752 us; speedup 1.0000x reference)
//
#include <hip/hip_runtime.h>
#include <hip/hip_bf16.h>

// Shapes (fixed by reference): B=2, S=2048, D=1024, H=16, K(d_head)=64
// Inputs FP32, output FP32. Intermediates bf16 in d_ws (40 MB layout).
#define B_ 2
#define S_ 2048
#define D_ 1024
#define H_ 16
#define K_ 64
// BS = 4096, HK = 1024

// softmax scale folded into Q at projection time: 0.125 * log2(e)
#define QSCALE 0.18033688f

typedef __attribute__((ext_vector_type(4))) float f32x4;
typedef __attribute__((ext_vector_type(8))) short bf16x8;

__device__ __forceinline__ float bf_lo(unsigned int u) {
    union { float f; unsigned int i; } c; c.i = u << 16; return c.f;
}
__device__ __forceinline__ float bf_hi(unsigned int u) {
    union { float f; unsigned int i; } c; c.i = u & 0xffff0000u; return c.f;
}
__device__ __forceinline__ unsigned short f2b(float f) {
    __hip_bfloat16 h = __float2bfloat16(f);   // RNE
    union { __hip_bfloat16 h; unsigned short s; } c; c.h = h; return c.s;
}

// 2^x via v_exp_f32 (scale pre-folded into Q upstream)
__device__ __forceinline__ float fexp2(float x) {
#if __has_builtin(__builtin_amdgcn_exp2f)
    return __builtin_amdgcn_exp2f(x);
#else
    float r; asm("v_exp_f32 %0, %1" : "=v"(r) : "v"(x)); return r;
#endif
}

// Direct global->LDS, 16B per lane. LDS dest is wave-uniform base + lane*16
// (linear).
__device__ __forceinline__ void gl_lds16(const unsigned short* g, const unsigned short* l)
{
    __builtin_amdgcn_global_load_lds(
        (const __attribute__((address_space(1))) unsigned int*)(unsigned long long)g,
        (__attribute__((address_space(3))) unsigned int*)(unsigned int)(unsigned long long)l,
        16, 0, 0);
}

// ===========================================================================
// PREP (merged): one launch does x->bf16 cvt + Wqkv transposes + Wo transpose.
// Grid (16,16,65): z==0 -> Wo (R=1024,C=1024); z in [1,49) -> Wqkv mats
// (src=(z-1)/16, m=(z-1)%16, R=1024, C=64, only x==0 active); z in [49,65)
// -> cvt slice c=(z-49)*256 + y*16 + x.
// Replaces 3 serialized launches (R5 ledger: non-attn ~128us incl. gaps).
// ===========================================================================
__global__ __launch_bounds__(256) void prep_all(
    const float* __restrict__ x,  const float* __restrict__ Wq,
    const float* __restrict__ Wk, const float* __restrict__ Wv,
    const float* __restrict__ Wo,
    unsigned short* __restrict__ xb,
    unsigned short* __restrict__ Wtq, unsigned short* __restrict__ Wtk,
    unsigned short* __restrict__ Wtv, unsigned short* __restrict__ Wot)
{
    const int z = blockIdx.z;
    const int t = threadIdx.x;

    if (z >= 49) {   // ---- cvt x -> bf16, 4 elems/thread ----
        const int c = (z - 49) * 256 + blockIdx.y * 16 + blockIdx.x;
        const int i = (c * 256 + t) * 4;
        const float4 v = *(const float4*)(x + i);
        ushort4 o;
        o.x = f2b(v.x); o.y = f2b(v.y); o.z = f2b(v.z); o.w = f2b(v.w);
        *(ushort4*)(xb + i) = o;
        return;
    }

    // ---- transpose+cvt: in fp32 [R=1024][C] -> out bf16 [C][1024] ----
    const float* in;
    unsigned short* out;
    int C;
    size_t mb;
    if (z == 0) {
        in = Wo; out = Wot; C = 1024; mb = 0;
    } else {
        if (blockIdx.x != 0) return;   // C=64 -> single c-block
        const int zz = z - 1;
        const int src = zz >> 4, m = zz & 15;
        in  = (src == 0) ? Wq : (src == 1) ? Wk : Wv;
        out = (src == 0) ? Wtq : (src == 1) ? Wtk : Wtv;
        C = 64; mb = (size_t)m * 1024 * 64;
    }

    __shared__ float tl[64][65];
    const int c0 = blockIdx.x * 64, r0 = blockIdx.y * 64;

    #pragma unroll
    for (int p = 0; p < 4; ++p) {
        const int idx = p * 256 + t;
        const int r = idx >> 4, cc = (idx & 15) * 4;
        const float4 v = *(const float4*)(in + mb + (size_t)(r0 + r) * C + c0 + cc);
        tl[r][cc] = v.x; tl[r][cc + 1] = v.y; tl[r][cc + 2] = v.z; tl[r][cc + 3] = v.w;
    }
    __syncthreads();
    const int c = t >> 2, rc = (t & 3) * 16;
    unsigned int u[8];
    #pragma unroll
    for (int j = 0; j < 8; ++j)
        u[j] = (unsigned int)f2b(tl[rc + 2 * j][c]) |
               ((unsigned int)f2b(tl[rc + 2 * j + 1][c]) << 16);
    unsigned short* op = out + mb + (size_t)(c0 + c) * 1024 + r0 + rc;
    *(uint4*)op       = *(uint4*)&u[0];
    *(uint4*)(op + 8) = *(uint4*)&u[4];
}

// ===========================================================================
// Kernel A (MFMA): fused QKV projection.
// global_load_lds(16B) staging, linear LDS + XOR-swizzle (both sides),
// double-buffered tiles + prefetch (T3 2-phase).
// Q written PRE-SCALED by QSCALE. Q,K [B][H][S][K].
// V written transposed AND k-permuted within 32-col blocks (Vtp):
//   store pos kappa of value t: kappa{4:3}=t{3:2}, kappa{2}=t{4}, kappa{1:0}=t{1:0}
// so attn's PV A-operand is lane-local (P never goes through LDS).
// ===========================================================================
__global__ __launch_bounds__(256) void gemm_qkv(
    const unsigned short* __restrict__ xb,    // bf16 [4096][1024]
    const unsigned short* __restrict__ Wtq,   // bf16 [16][64][1024]
    const unsigned short* __restrict__ Wtk,
    const unsigned short* __restrict__ Wtv,
    unsigned short* __restrict__ Qo,          // bf16 [B][H][S][K]
    unsigned short* __restrict__ Ko,          // bf16 [B][H][S][K]
    unsigned short* __restrict__ Vto)         // bf16 [B][H][K][S] (permuted)
{
    __shared__ unsigned short xs[2][128 * 64];    // 32KB [m][k] linear, swz
    __shared__ unsigned short ws[2][3][64 * 64];  // 48KB [n][k] per W, swz

    const int h = blockIdx.x, mt = blockIdx.y;
    const int tid = threadIdx.x;
    const int wv = tid >> 6, lane = tid & 63;
    const int quad = lane >> 4, l15 = lane & 15;
    const int l8 = lane >> 3;
    const int c8 = ((lane & 7) ^ l8) * 8;   // pre-swizzled source col (elems)
    const int x7 = l15 & 7;                 // read-side XOR key
    const int m0 = mt * 128;

    const unsigned short* wsrc[3] = {
        Wtq + (size_t)h * 65536, Wtk + (size_t)h * 65536, Wtv + (size_t)h * 65536 };

    f32x4 acc[3][2][4] = {};   // [out][mfrag][nfrag]

    auto stage = [&](int bi, int k0) {
        const unsigned short* xg =
            xb + (size_t)(m0 + wv * 32 + l8) * 1024 + k0 + c8;
        #pragma unroll
        for (int j = 0; j < 4; ++j)
            gl_lds16(xg + (size_t)j * 8 * 1024, &xs[bi][(wv * 4 + j) * 512]);
        #pragma unroll
        for (int w = 0; w < 3; ++w) {
            const unsigned short* wg =
                wsrc[w] + (size_t)(wv * 16 + l8) * 1024 + k0 + c8;
            gl_lds16(wg,            &ws[bi][w][(wv * 2 + 0) * 512]);
            gl_lds16(wg + 8 * 1024, &ws[bi][w][(wv * 2 + 1) * 512]);
        }
    };

    stage(0, 0);
    __syncthreads();   // compiler emits vmcnt(0) drain here

    for (int kt = 0; kt < 16; ++kt) {
        const int cur = kt & 1;
        if (kt < 15) stage(cur ^ 1, (kt + 1) * 64);   // prefetch next tile

        const unsigned short* xsc = xs[cur];
        #pragma unroll
        for (int kh = 0; kh < 2; ++kh) {
            const int csw = ((kh * 4 + quad) ^ x7) * 8;   // rows used have r&7==x7
            const bf16x8 a0 = *(const bf16x8*)&xsc[(wv * 32 + l15) * 64 + csw];
            const bf16x8 a1 = *(const bf16x8*)&xsc[(wv * 32 + 16 + l15) * 64 + csw];
            #pragma unroll
            for (int nb = 0; nb < 4; ++nb) {
                #pragma unroll
                for (int w = 0; w < 3; ++w) {
                    const bf16x8 bfr = *(const bf16x8*)&ws[cur][w][(nb * 16 + l15) * 64 + csw];
                    acc[w][0][nb] = __builtin_amdgcn_mfma_f32_16x16x32_bf16(a0, bfr, acc[w][0][nb], 0, 0, 0);
                    acc[w][1][nb] = __builtin_amdgcn_mfma_f32_16x16x32_bf16(a1, bfr, acc[w][1][nb], 0, 0, 0);
                }
            }
        }
        __syncthreads();   // drains this iter's prefetch (issued pre-compute)
    }

    // Q (scaled), K epilogue: C row = quad*4+reg, col = l15. [B][H][S][K]
    #pragma unroll
    for (int mf = 0; mf < 2; ++mf)
        #pragma unroll
        for (int r = 0; r < 4; ++r) {
            const int s  = m0 + wv * 32 + mf * 16 + quad * 4 + r;
            const int bb = s >> 11;
            const int ss = s & (S_ - 1);
            const size_t base = (((size_t)(bb * H_ + h)) * S_ + ss) * K_;
            #pragma unroll
            for (int nb = 0; nb < 4; ++nb) {
                Qo[base + nb * 16 + l15] = f2b(acc[0][mf][nb][r] * QSCALE);
                Ko[base + nb * 16 + l15] = f2b(acc[1][mf][nb][r]);
            }
        }

    // V epilogue: transposed + k-permuted. Lane's 4 consecutive s values
    // (s = sb + r, sb = ...+quad*4, r=0..3) land at permuted inner pos
    // kappa = quad*8 + mf*4 + r within the 32-block -> still one 8B store.
    {
        const int sb32 = m0 + wv * 32;           // 32-aligned block base
        const int bb   = sb32 >> 11;
        const int ssb  = sb32 & (S_ - 1);        // 32-aligned
        #pragma unroll
        for (int mf = 0; mf < 2; ++mf) {
            const int kap = quad * 8 + mf * 4;   // permuted offset in 32-block
            #pragma unroll
            for (int nb = 0; nb < 4; ++nb) {
                const int k = nb * 16 + l15;
                const size_t vaddr = (((size_t)(bb * H_ + h)) * K_ + k) * S_ + ssb + kap;
                uint2 u;
                u.x = (unsigned int)f2b(acc[2][mf][nb][0]) | ((unsigned int)f2b(acc[2][mf][nb][1]) << 16);
                u.y = (unsigned int)f2b(acc[2][mf][nb][2]) | ((unsigned int)f2b(acc[2][mf][nb][3]) << 16);
                *(uint2*)&Vto[vaddr] = u;
            }
        }
    }
}

// ===========================================================================
// Kernel B (MFMA flash attention v9):
// R5 post-mortem: v8 at 52us, VALU 51 / Mfma 25 / Occ 16.5, conflicts 0.
// Remaining per-tile cost: exp (trans pipe) + pack VALU + residual barrier
// drain. v9 amortizes the drain: stage 128 t per barrier period (2 sub-tiles,
// dbuf), inner body runs twice unchanged -> barrier count 32->16, each drain
// covered by ~2x compute. LDS 64KB, still 2 blocks/CU (grid-limited).
// ===========================================================================
__global__ __launch_bounds__(256) void attn_mfma2(
    const unsigned short* __restrict__ Qb,
    const unsigned short* __restrict__ Kb,
    const unsigned short* __restrict__ Vt,   // [B][H][K][S] permuted
    unsigned short* __restrict__ Cb)         // [B][S][H][K]
{
    __shared__ unsigned short ks[2][2][64 * 64];  // [buf][half] K [t][k] swz
    __shared__ unsigned short vs[2][2][64 * 64];  // [buf][half] Vtp [d][kap]

    // XCD-aware bijective swizzle: nwg=512, 8 XCDs, chunk=64 (= 4 full bh).
    const int bid = blockIdx.x;
    const int lid = (bid & 7) * 64 + (bid >> 3);
    const int qt  = lid & 15;
    const int bh  = lid >> 4;
    const int h   = bh & 15;
    const int b   = bh >> 4;

    const int tid  = threadIdx.x;
    const int wv = tid >> 6, lane = tid & 63;
    const int quad = lane >> 4, l15 = lane & 15;
    const int l8 = lane >> 3;
    const int c8 = ((lane & 7) ^ l8) * 8;
    const int x7 = l15 & 7;

    const size_t base = ((size_t)(b * H_ + h)) * S_ * K_;   // Q,K and Vt extent

    // Q fragments: wave owns 32 q-rows = 2 groups of 16 (B-op of swapped QK^T)
    bf16x8 qf[2][2];
    #pragma unroll
    for (int g = 0; g < 2; ++g) {
        const int qrow = qt * 128 + wv * 32 + g * 16 + l15;
        qf[g][0] = *(const bf16x8*)(Qb + base + (size_t)qrow * K_ + quad * 8);
        qf[g][1] = *(const bf16x8*)(Qb + base + (size_t)qrow * K_ + 32 + quad * 8);
    }

    f32x4 ctxa[2][4] = {};
    float li[2] = {0.0f, 0.0f};   // PER-QUAD partial row-sum (reduced at end)

    auto stage = [&](int bi, int t0) {
        #pragma unroll
        for (int hf = 0; hf < 2; ++hf) {
            const unsigned short* kg =
                Kb + base + (size_t)(t0 + hf * 64 + wv * 16 + l8) * K_ + c8;
            gl_lds16(kg,          &ks[bi][hf][(wv * 2 + 0) * 512]);
            gl_lds16(kg + 8 * K_, &ks[bi][hf][(wv * 2 + 1) * 512]);
            const unsigned short* vg =
                Vt + base + (size_t)(wv * 16 + l8) * S_ + t0 + hf * 64 + c8;
            gl_lds16(vg,          &vs[bi][hf][(wv * 2 + 0) * 512]);
            gl_lds16(vg + 8 * S_, &vs[bi][hf][(wv * 2 + 1) * 512]);
        }
    };

    stage(0, 0);
    __syncthreads();   // vmcnt(0) drain of prologue stage

    for (int it = 0; it < S_ / 128; ++it) {
        const int cur = it & 1;
        if (it < S_ / 128 - 1) stage(cur ^ 1, (it + 1) * 128);   // prefetch

        #pragma unroll
        for (int hf = 0; hf < 2; ++hf) {
            const unsigned short* ksc = ks[cur][hf];
            const unsigned short* vsc = vs[cur][hf];

            // ---- S^T = K.Q^T : lane holds S[t=16tb+quad*4+r][q=l15] ----
            f32x4 sac[2][4] = {};
            __builtin_amdgcn_s_setprio(1);
            #pragma unroll
            for (int tb = 0; tb < 4; ++tb) {
                const bf16x8 kf0 = *(const bf16x8*)&ksc[(tb * 16 + l15) * 64 + ((quad) ^ x7) * 8];
                const bf16x8 kf1 = *(const bf16x8*)&ksc[(tb * 16 + l15) * 64 + ((4 + quad) ^ x7) * 8];
                #pragma unroll
                for (int g = 0; g < 2; ++g) {
                    sac[g][tb] = __builtin_amdgcn_mfma_f32_16x16x32_bf16(kf0, qf[g][0], sac[g][tb], 0, 0, 0);
                    sac[g][tb] = __builtin_amdgcn_mfma_f32_16x16x32_bf16(kf1, qf[g][1], sac[g][tb], 0, 0, 0);
                }
            }
            __builtin_amdgcn_s_setprio(0);

            // ---- softmax: p = 2^s; in-lane partial sum; pack A-frags ----
            bf16x8 pa[2][2];   // [g][kh] PV A-operand, fully lane-local
            #pragma unroll
            for (int g = 0; g < 2; ++g) {
                float ps[4][4];
                float rs = 0.0f;
                #pragma unroll
                for (int tb = 0; tb < 4; ++tb)
                    #pragma unroll
                    for (int r = 0; r < 4; ++r) {
                        const float p = fexp2(sac[g][tb][r]);
                        ps[tb][r] = p;
                        rs += p;
                    }
                li[g] += rs;   // per-quad partial; cross-quad reduce deferred

                #pragma unroll
                for (int kh = 0; kh < 2; ++kh) {
                    union { bf16x8 v; unsigned short s[8]; } u;
                    u.s[0] = f2b(ps[2 * kh][0]);     u.s[1] = f2b(ps[2 * kh][1]);
                    u.s[2] = f2b(ps[2 * kh][2]);     u.s[3] = f2b(ps[2 * kh][3]);
                    u.s[4] = f2b(ps[2 * kh + 1][0]); u.s[5] = f2b(ps[2 * kh + 1][1]);
                    u.s[6] = f2b(ps[2 * kh + 1][2]); u.s[7] = f2b(ps[2 * kh + 1][3]);
                    pa[g][kh] = u.v;
                }
            }

            // ---- PV: ctx[q][d], A = pa (regs), B = Vtp rows ----
            __builtin_amdgcn_s_setprio(1);
            #pragma unroll
            for (int kh = 0; kh < 2; ++kh)
                #pragma unroll
                for (int cb = 0; cb < 4; ++cb) {
                    const bf16x8 bfr = *(const bf16x8*)&vsc[(cb * 16 + l15) * 64 + ((kh * 4 + quad) ^ x7) * 8];
                    #pragma unroll
                    for (int g = 0; g < 2; ++g)
                        ctxa[g][cb] = __builtin_amdgcn_mfma_f32_16x16x32_bf16(pa[g][kh], bfr, ctxa[g][cb], 0, 0, 0);
                }
            __builtin_amdgcn_s_setprio(0);
        }

        __syncthreads();   // drains this iter's prefetch; protects buf reuse
    }

    // ---- epilogue: reduce li across quads ONCE, normalize, write ----
    #pragma unroll
    for (int g = 0; g < 2; ++g) {
        float lf = li[g];
        lf += __shfl_xor(lf, 16);
        lf += __shfl_xor(lf, 32);
        #pragma unroll
        for (int r = 0; r < 4; ++r) {
            const float inv = 1.0f / __shfl(lf, quad * 4 + r);
            const int s = qt * 128 + wv * 32 + g * 16 + quad * 4 + r;
            const size_t ob = (((size_t)(b * S_ + s)) * H_ + h) * K_;
            #pragma unroll
            for (int cb = 0; cb < 4; ++cb)
                Cb[ob + cb * 16 + l15] = f2b(ctxa[g][cb][r] * inv);
        }
    }
}

// ===========================================================================
// Fallback attention (R5-verified): reads V [B][H][S][K], in-kernel
// transpose, running-max softmax. (Expects UNSCALED Q from qkv_proj.)
// ===========================================================================
__global__ __launch_bounds__(256) void attn_mfma_v1(
    const unsigned short* __restrict__ Qb,
    const unsigned short* __restrict__ Kb,
    const unsigned short* __restrict__ Vb,
    unsigned short* __restrict__ Cb)
{
    __shared__ unsigned short ks[64 * 72];
    __shared__ unsigned short vt[64 * 72];
    __shared__ unsigned short pbuf[4 * 16 * 72];

    const int b = blockIdx.z, h = blockIdx.y, qt = blockIdx.x;
    const int tid  = threadIdx.x;
    const int wave = tid >> 6, lane = tid & 63;
    const int quad = lane >> 4, l15 = lane & 15;

    const size_t base = ((size_t)(b * H_ + h)) * S_ * K_;

    const int qrow = qt * 64 + wave * 16 + l15;
    const bf16x8 qf0 = *(const bf16x8*)(Qb + base + (size_t)qrow * K_ + quad * 8);
    const bf16x8 qf1 = *(const bf16x8*)(Qb + base + (size_t)qrow * K_ + 32 + quad * 8);

    f32x4 ctxa[4] = {};
    float mi[4], li[4];
    #pragma unroll
    for (int r = 0; r < 4; ++r) { mi[r] = -INFINITY; li[r] = 0.0f; }

    unsigned short* pw = pbuf + wave * 16 * 72;

    for (int tb0 = 0; tb0 < S_; tb0 += 64) {
        __syncthreads();
        #pragma unroll
        for (int p = 0; p < 2; ++p) {
            const int idx = tid + p * 256;
            const int t = idx >> 3, c = idx & 7;
            *(uint4*)&ks[t * 72 + c * 8] =
                *(const uint4*)(Kb + base + (size_t)(tb0 + t) * K_ + c * 8);
        }
        #pragma unroll
        for (int p = 0; p < 2; ++p) {
            const int c = wave + p * 4;
            uint4 u = *(const uint4*)(Vb + base + (size_t)(tb0 + lane) * K_ + c * 8);
            const unsigned short* us = (const unsigned short*)&u;
            #pragma unroll
            for (int d = 0; d < 8; ++d)
                vt[(c * 8 + d) * 72 + lane] = us[d];
        }
        __syncthreads();

        f32x4 sac[4] = {};
        #pragma unroll
        for (int tb = 0; tb < 4; ++tb) {
            const bf16x8 kf0 = *(const bf16x8*)&ks[(tb * 16 + l15) * 72 + quad * 8];
            const bf16x8 kf1 = *(const bf16x8*)&ks[(tb * 16 + l15) * 72 + 32 + quad * 8];
            sac[tb] = __builtin_amdgcn_mfma_f32_16x16x32_bf16(qf0, kf0, sac[tb], 0, 0, 0);
            sac[tb] = __builtin_amdgcn_mfma_f32_16x16x32_bf16(qf1, kf1, sac[tb], 0, 0, 0);
        }

        float mnew[4], alpha[4];
        #pragma unroll
        for (int r = 0; r < 4; ++r) {
            float v = fmaxf(fmaxf(sac[0][r], sac[1][r]), fmaxf(sac[2][r], sac[3][r])) * 0.125f;
            v = fmaxf(v, __shfl_xor(v, 1));
            v = fmaxf(v, __shfl_xor(v, 2));
            v = fmaxf(v, __shfl_xor(v, 4));
            v = fmaxf(v, __shfl_xor(v, 8));
            mnew[r]  = fmaxf(mi[r], v);
            alpha[r] = __expf(mi[r] - mnew[r]);
            mi[r]    = mnew[r];
        }
        float pv[4][4], rs[4];
        #pragma unroll
        for (int r = 0; r < 4; ++r) rs[r] = 0.0f;
        #pragma unroll
        for (int tb = 0; tb < 4; ++tb)
            #pragma unroll
            for (int r = 0; r < 4; ++r) {
                const float p = __expf(sac[tb][r] * 0.125f - mnew[r]);
                pv[tb][r] = p;
                rs[r] += p;
            }
        #pragma unroll
        for (int r = 0; r < 4; ++r) {
            float s = rs[r];
            s += __shfl_xor(s, 1);
            s += __shfl_xor(s, 2);
            s += __shfl_xor(s, 4);
            s += __shfl_xor(s, 8);
            li[r] = li[r] * alpha[r] + s;
        }
        #pragma unroll
        for (int cb = 0; cb < 4; ++cb)
            #pragma unroll
            for (int r = 0; r < 4; ++r)
                ctxa[cb][r] *= alpha[r];

        #pragma unroll
        for (int tb = 0; tb < 4; ++tb)
            #pragma unroll
            for (int r = 0; r < 4; ++r)
                pw[(quad * 4 + r) * 72 + tb * 16 + l15] = f2b(pv[tb][r]);

        #pragma unroll
        for (int kh = 0; kh < 2; ++kh) {
            const bf16x8 af = *(const bf16x8*)&pw[l15 * 72 + kh * 32 + quad * 8];
            #pragma unroll
            for (int cb = 0; cb < 4; ++cb) {
                const bf16x8 bfr = *(const bf16x8*)&vt[(cb * 16 + l15) * 72 + kh * 32 + quad * 8];
                ctxa[cb] = __builtin_amdgcn_mfma_f32_16x16x32_bf16(af, bfr, ctxa[cb], 0, 0, 0);
            }
        }
    }

    #pragma unroll
    for (int r = 0; r < 4; ++r) {
        const float inv = 1.0f / li[r];
        const int s = qt * 64 + wave * 16 + quad * 4 + r;
        const size_t ob = (((size_t)(b * S_ + s)) * H_ + h) * K_;
        #pragma unroll
        for (int cb = 0; cb < 4; ++cb)
            Cb[ob + cb * 16 + l15] = f2b(ctxa[cb][r] * inv);
    }
}

// ===========================================================================
// Kernel C (MFMA): output projection + head sum.
// global_load_lds(16B) staging + double-buffer/prefetch (T3 2-phase).
// ===========================================================================
__global__ __launch_bounds__(256) void gemm_out(
    const unsigned short* __restrict__ ctx,   // bf16 [4096][1024]
    const unsigned short* __restrict__ Wot,   // bf16 [1024 d][1024 hk]
    float* __restrict__ out)                  // fp32 [4096][1024]
{
    __shared__ unsigned short cs[2][128 * 64];   // 32KB
    __shared__ unsigned short ws[2][64 * 64];    // 16KB

    const int nt = blockIdx.x, mt = blockIdx.y;
    const int tid = threadIdx.x;
    const int wv = tid >> 6, lane = tid & 63;
    const int quad = lane >> 4, l15 = lane & 15;
    const int l8 = lane >> 3;
    const int c8 = ((lane & 7) ^ l8) * 8;
    const int x7 = l15 & 7;
    const int m0 = mt * 128, n0 = nt * 64;

    f32x4 acc[2][4] = {};

    auto stage = [&](int bi, int k0) {
        const unsigned short* cg =
            ctx + (size_t)(m0 + wv * 32 + l8) * 1024 + k0 + c8;
        #pragma unroll
        for (int j = 0; j < 4; ++j)
            gl_lds16(cg + (size_t)j * 8 * 1024, &cs[bi][(wv * 4 + j) * 512]);
        const unsigned short* wg =
            Wot + (size_t)(n0 + wv * 16 + l8) * 1024 + k0 + c8;
        gl_lds16(wg,            &ws[bi][(wv * 2 + 0) * 512]);
        gl_lds16(wg + 8 * 1024, &ws[bi][(wv * 2 + 1) * 512]);
    };

    stage(0, 0);
    __syncthreads();

    for (int kt = 0; kt < 16; ++kt) {
        const int cur = kt & 1;
        if (kt < 15) stage(cur ^ 1, (kt + 1) * 64);

        const unsigned short* csc = cs[cur];
        const unsigned short* wsc = ws[cur];
        #pragma unroll
        for (int kh = 0; kh < 2; ++kh) {
            const int csw = ((kh * 4 + quad) ^ x7) * 8;
            const bf16x8 a0 = *(const bf16x8*)&csc[(wv * 32 + l15) * 64 + csw];
            const bf16x8 a1 = *(const bf16x8*)&csc[(wv * 32 + 16 + l15) * 64 + csw];
            #pragma unroll
            for (int nb = 0; nb < 4; ++nb) {
                const bf16x8 bfr = *(const bf16x8*)&wsc[(nb * 16 + l15) * 64 + csw];
                acc[0][nb] = __builtin_amdgcn_mfma_f32_16x16x32_bf16(a0, bfr, acc[0][nb], 0, 0, 0);
                acc[1][nb] = __builtin_amdgcn_mfma_f32_16x16x32_bf16(a1, bfr, acc[1][nb], 0, 0, 0);
            }
        }
        __syncthreads();
    }

    #pragma unroll
    for (int mf = 0; mf < 2; ++mf)
        #pragma unroll
        for (int r = 0; r < 4; ++r) {
            const int m = m0 + wv * 32 + mf * 16 + quad * 4 + r;
            #pragma unroll
            for (int nb = 0; nb < 4; ++nb)
                out[(size_t)m * 1024 + n0 + nb * 16 + l15] = acc[mf][nb][r];
        }
}

// ===========================================================================
// FALLBACK (32 MB ws): fp32 VALU projections (R5-verified)
// ===========================================================================
__global__ __launch_bounds__(256) void qkv_proj(
    const float* __restrict__ x, const float* __restrict__ Wq,
    const float* __restrict__ Wk, const float* __restrict__ Wv,
    unsigned short* __restrict__ Qo, unsigned short* __restrict__ Ko,
    unsigned short* __restrict__ Vo)
{
    __shared__ float xs[32][68];
    __shared__ float wqs[32][68];
    __shared__ float wks[32][68];
    __shared__ float wvs[32][68];

    const int h  = blockIdx.x;
    const int m0 = blockIdx.y * 64;
    const int t  = threadIdx.x;
    const int tx = t & 15, ty = t >> 4;
    const int xr = t >> 2, xc = (t & 3) * 8;
    const int wr = t >> 3, wc = (t & 7) * 8;

    float aq[4][4] = {}, ak[4][4] = {}, av[4][4] = {};
    const int wbase = h * D_ * K_;

    for (int d0 = 0; d0 < D_; d0 += 32) {
        __syncthreads();
        {
            const float* xf = x + (size_t)(m0 + xr) * D_ + d0 + xc;
            const float4 a = *(const float4*)xf;
            const float4 b = *(const float4*)(xf + 4);
            xs[xc + 0][xr] = a.x; xs[xc + 1][xr] = a.y;
            xs[xc + 2][xr] = a.z; xs[xc + 3][xr] = a.w;
            xs[xc + 4][xr] = b.x; xs[xc + 5][xr] = b.y;
            xs[xc + 6][xr] = b.z; xs[xc + 7][xr] = b.w;
        }
        {
            const size_t idx = (size_t)wbase + (size_t)(d0 + wr) * K_ + wc;
            *(float4*)&wqs[wr][wc]     = *(const float4*)&Wq[idx];
            *(float4*)&wqs[wr][wc + 4] = *(const float4*)&Wq[idx + 4];
            *(float4*)&wks[wr][wc]     = *(const float4*)&Wk[idx];
            *(float4*)&wks[wr][wc + 4] = *(const float4*)&Wk[idx + 4];
            *(float4*)&wvs[wr][wc]     = *(const float4*)&Wv[idx];
            *(float4*)&wvs[wr][wc + 4] = *(const float4*)&Wv[idx + 4];
        }
        __syncthreads();

        #pragma unroll 8
        for (int kk = 0; kk < 32; ++kk) {
            const float4 xv = *(const float4*)&xs[kk][ty * 4];
            const float4 q4 = *(const float4*)&wqs[kk][tx * 4];
            const float4 k4 = *(const float4*)&wks[kk][tx * 4];
            const float4 v4 = *(const float4*)&wvs[kk][tx * 4];
            const float xa[4] = {xv.x, xv.y, xv.z, xv.w};
            const float qa[4] = {q4.x, q4.y, q4.z, q4.w};
            const float ka[4] = {k4.x, k4.y, k4.z, k4.w};
            const float va[4] = {v4.x, v4.y, v4.z, v4.w};
            #pragma unroll
            for (int i = 0; i < 4; ++i)
                #pragma unroll
                for (int j = 0; j < 4; ++j) {
                    aq[i][j] += xa[i] * qa[j];
                    ak[i][j] += xa[i] * ka[j];
                    av[i][j] += xa[i] * va[j];
                }
        }
    }

    #pragma unroll
    for (int i = 0; i < 4; ++i) {
        const int m  = m0 + ty * 4 + i;
        const int bb = m >> 11;
        const int ss = m & (S_ - 1);
        const size_t base = (((size_t)(bb * H_ + h)) * S_ + ss) * K_ + tx * 4;
        ushort4 pq, pk, pv;
        pq.x = f2b(aq[i][0]); pq.y = f2b(aq[i][1]); pq.z = f2b(aq[i][2]); pq.w = f2b(aq[i][3]);
        pk.x = f2b(ak[i][0]); pk.y = f2b(ak[i][1]); pk.z = f2b(ak[i][2]); pk.w = f2b(ak[i][3]);
        pv.x = f2b(av[i][0]); pv.y = f2b(av[i][1]); pv.z = f2b(av[i][2]); pv.w = f2b(av[i][3]);
        *(ushort4*)&Qo[base] = pq;
        *(ushort4*)&Ko[base] = pk;
        *(ushort4*)&Vo[base] = pv;
    }
}

__global__ __launch_bounds__(256) void out_proj(
    const unsigned int* __restrict__ Cb, const float* __restrict__ Wo,
    float* __restrict__ out)
{
    __shared__ float cs[32][68];
    __shared__ float wos[32][68];

    const int n0 = blockIdx.x * 64;
    const int m0 = blockIdx.y * 64;
    const int t  = threadIdx.x;
    const int tx = t & 15, ty = t >> 4;
    const int xr = t >> 2, xc = (t & 3) * 8;
    const int wr = t >> 3, wc = (t & 7) * 8;

    float acc[4][4] = {};

    for (int k0 = 0; k0 < 1024; k0 += 32) {
        __syncthreads();
        {
            uint4 u = *(const uint4*)&Cb[((size_t)(m0 + xr) * 1024 + k0 + xc) >> 1];
            cs[xc + 0][xr] = bf_lo(u.x); cs[xc + 1][xr] = bf_hi(u.x);
            cs[xc + 2][xr] = bf_lo(u.y); cs[xc + 3][xr] = bf_hi(u.y);
            cs[xc + 4][xr] = bf_lo(u.z); cs[xc + 5][xr] = bf_hi(u.z);
            cs[xc + 6][xr] = bf_lo(u.w); cs[xc + 7][xr] = bf_hi(u.w);
        }
        {
            const float* wof = Wo + (size_t)(k0 + wr) * 1024 + n0 + wc;
            *(float4*)&wos[wr][wc]     = *(const float4*)wof;
            *(float4*)&wos[wr][wc + 4] = *(const float4*)(wof + 4);
        }
        __syncthreads();

        #pragma unroll 8
        for (int kk = 0; kk < 32; ++kk) {
            const float4 cv = *(const float4*)&cs[kk][ty * 4];
            const float4 wv = *(const float4*)&wos[kk][tx * 4];
            const float ca[4] = {cv.x, cv.y, cv.z, cv.w};
            const float wa[4] = {wv.x, wv.y, wv.z, wv.w};
            #pragma unroll
            for (int i = 0; i < 4; ++i)
                #pragma unroll
                for (int j = 0; j < 4; ++j)
                    acc[i][j] += ca[i] * wa[j];
        }
    }

    #pragma unroll
    for (int i = 0; i < 4; ++i) {
        const int m = m0 + ty * 4 + i;
        float4 p = make_float4(acc[i][0], acc[i][1], acc[i][2], acc[i][3]);
        *(float4*)&out[(size_t)m * 1024 + n0 + tx * 4] = p;
    }
}

// ===========================================================================
extern "C" void kernel_launch(void* const* d_in, const int* in_sizes, int n_in,
                              void* d_out, int out_size, void* d_ws, size_t ws_size,
                              hipStream_t stream)
{
    (void)in_sizes; (void)n_in; (void)out_size;
    const float* x  = (const float*)d_in[0];
    const float* Wq = (const float*)d_in[1];
    const float* Wk = (const float*)d_in[2];
    const float* Wv = (const float*)d_in[3];
    const float* Wo = (const float*)d_in[4];
    float* out = (float*)d_out;

    const size_t QKV_ELEMS = (size_t)B_ * H_ * S_ * K_;   // 4,194,304

    if (ws_size >= (size_t)40 * 1024 * 1024) {
        // ws layout (bf16 elems), exactly 40 MB:
        //  xb (8MB; aliased by ctx after gemm_qkv) | Wtq|Wtk|Wtv (2MB each) |
        //  Wot (2MB) | Q (8MB) | K (8MB) | Vt (8MB, [B][H][K][S] permuted)
        unsigned short* xb  = (unsigned short*)d_ws;
        unsigned short* Wtq = xb  + (size_t)4096 * 1024;
        unsigned short* Wtk = Wtq + (size_t)16 * 64 * 1024;
        unsigned short* Wtv = Wtk + (size_t)16 * 64 * 1024;
        unsigned short* Wot = Wtv + (size_t)16 * 64 * 1024;
        unsigned short* Qb  = Wot + (size_t)1024 * 1024;
        unsigned short* Kb  = Qb + QKV_ELEMS;
        unsigned short* Vtb = Kb + QKV_ELEMS;
        unsigned short* Cb  = xb;   // alias: xb dead after gemm_qkv

        prep_all<<<dim3(16, 16, 65), 256, 0, stream>>>(
            x, Wq, Wk, Wv, Wo, xb, Wtq, Wtk, Wtv, Wot);

        gemm_qkv<<<dim3(16, 32), 256, 0, stream>>>(xb, Wtq, Wtk, Wtv, Qb, Kb, Vtb);
        attn_mfma2<<<dim3(512), 256, 0, stream>>>(Qb, Kb, Vtb, Cb);
        gemm_out<<<dim3(16, 32), 256, 0, stream>>>(Cb, Wot, out);
    } else {
        // fallback (32 MB): Q | K | V | ctx   (R5-verified path)
        unsigned short* Qb = (unsigned short*)d_ws;
        unsigned short* Kb = Qb + QKV_ELEMS;
        unsigned short* Vb = Kb + QKV_ELEMS;
        unsigned short* Cb = Vb + QKV_ELEMS;

        qkv_proj<<<dim3(16, 64), 256, 0, stream>>>(x, Wq, Wk, Wv, Qb, Kb, Vb);
        attn_mfma_v1<<<dim3(32, 16, 2), 256, 0, stream>>>(Qb, Kb, Vb, Cb);
        out_proj<<<dim3(16, 64), 256, 0, stream>>>((const unsigned int*)Cb, Wo, out);
    }
}

// Round 7
// 168.874 us; speedup vs baseline: 1.0940x; 1.0940x over previous
//
#include <hip/hip_runtime.h>
#include <hip/hip_bf16.h>

// Shapes (fixed by reference): B=2, S=2048, D=1024, H=16, K(d_head)=64
// Inputs FP32, output FP32. Intermediates bf16 in d_ws (40 MB layout).
#define B_ 2
#define S_ 2048
#define D_ 1024
#define H_ 16
#define K_ 64
// BS = 4096, HK = 1024

// softmax scale folded into Q at projection time: 0.125 * log2(e)
#define QSCALE 0.18033688f

typedef __attribute__((ext_vector_type(4))) float f32x4;
typedef __attribute__((ext_vector_type(8))) short bf16x8;

__device__ __forceinline__ float bf_lo(unsigned int u) {
    union { float f; unsigned int i; } c; c.i = u << 16; return c.f;
}
__device__ __forceinline__ float bf_hi(unsigned int u) {
    union { float f; unsigned int i; } c; c.i = u & 0xffff0000u; return c.f;
}
__device__ __forceinline__ unsigned short f2b(float f) {
    __hip_bfloat16 h = __float2bfloat16(f);   // RNE
    union { __hip_bfloat16 h; unsigned short s; } c; c.h = h; return c.s;
}

// 2^x via v_exp_f32 (scale pre-folded into Q upstream)
__device__ __forceinline__ float fexp2(float x) {
#if __has_builtin(__builtin_amdgcn_exp2f)
    return __builtin_amdgcn_exp2f(x);
#else
    float r; asm("v_exp_f32 %0, %1" : "=v"(r) : "v"(x)); return r;
#endif
}

// Direct global->LDS, 16B per lane. LDS dest is wave-uniform base + lane*16
// (linear).
__device__ __forceinline__ void gl_lds16(const unsigned short* g, const unsigned short* l)
{
    __builtin_amdgcn_global_load_lds(
        (const __attribute__((address_space(1))) unsigned int*)(unsigned long long)g,
        (__attribute__((address_space(3))) unsigned int*)(unsigned int)(unsigned long long)l,
        16, 0, 0);
}

// ===========================================================================
// PREP (merged, FLAT grid — R6's 3D grid had 11520 dead blocks):
// blocks [0,4096):   x -> bf16 cvt (4 elems/thread)
// blocks [4096,4864): Wqkv transpose: mat = (bz-4096)>>4, r0 = ((bz-4096)&15)*64
// blocks [4864,5120): Wo transpose: zz = bz-4864, c0 = (zz&15)*64, r0=(zz>>4)*64
// ===========================================================================
__global__ __launch_bounds__(256) void prep_all(
    const float* __restrict__ x,  const float* __restrict__ Wq,
    const float* __restrict__ Wk, const float* __restrict__ Wv,
    const float* __restrict__ Wo,
    unsigned short* __restrict__ xb,
    unsigned short* __restrict__ Wtq, unsigned short* __restrict__ Wtk,
    unsigned short* __restrict__ Wtv, unsigned short* __restrict__ Wot)
{
    const int bz = blockIdx.x;
    const int t = threadIdx.x;

    if (bz < 4096) {   // ---- cvt x -> bf16 ----
        const int i = (bz * 256 + t) * 4;
        const float4 v = *(const float4*)(x + i);
        ushort4 o;
        o.x = f2b(v.x); o.y = f2b(v.y); o.z = f2b(v.z); o.w = f2b(v.w);
        *(ushort4*)(xb + i) = o;
        return;
    }

    const float* in;
    unsigned short* out;
    int C, c0, r0;
    size_t mb;
    if (bz < 4864) {   // Wqkv: [1024][64] -> [64][1024], 16 r-blocks per mat
        const int zz = bz - 4096;
        const int mat = zz >> 4;           // 0..47
        const int src = mat >> 4, m = mat & 15;
        in  = (src == 0) ? Wq : (src == 1) ? Wk : Wv;
        out = (src == 0) ? Wtq : (src == 1) ? Wtk : Wtv;
        C = 64; c0 = 0; r0 = (zz & 15) * 64;
        mb = (size_t)m * 1024 * 64;
    } else {           // Wo: [1024][1024] -> [1024][1024]^T
        const int zz = bz - 4864;
        in = Wo; out = Wot; C = 1024;
        c0 = (zz & 15) * 64; r0 = (zz >> 4) * 64;
        mb = 0;
    }

    __shared__ float tl[64][65];

    #pragma unroll
    for (int p = 0; p < 4; ++p) {
        const int idx = p * 256 + t;
        const int r = idx >> 4, cc = (idx & 15) * 4;
        const float4 v = *(const float4*)(in + mb + (size_t)(r0 + r) * C + c0 + cc);
        tl[r][cc] = v.x; tl[r][cc + 1] = v.y; tl[r][cc + 2] = v.z; tl[r][cc + 3] = v.w;
    }
    __syncthreads();
    const int c = t >> 2, rc = (t & 3) * 16;
    unsigned int u[8];
    #pragma unroll
    for (int j = 0; j < 8; ++j)
        u[j] = (unsigned int)f2b(tl[rc + 2 * j][c]) |
               ((unsigned int)f2b(tl[rc + 2 * j + 1][c]) << 16);
    unsigned short* op = out + mb + (size_t)(c0 + c) * 1024 + r0 + rc;
    *(uint4*)op       = *(uint4*)&u[0];
    *(uint4*)(op + 8) = *(uint4*)&u[4];
}

// ===========================================================================
// Kernel A (MFMA): fused QKV projection — R7: 512 threads, 8 waves
// (4 m-groups x 2 n-halves). Same 80KB LDS dbuf + gl_lds16 + XOR swizzle,
// but 16 waves/CU (was 8) — TLP x2 at identical LDS traffic/FLOP.
// Q PRE-SCALED by QSCALE. Q,K [B][H][S][K]; V transposed + k-permuted (Vtp).
// ===========================================================================
__global__ __launch_bounds__(512, 4) void gemm_qkv(
    const unsigned short* __restrict__ xb,    // bf16 [4096][1024]
    const unsigned short* __restrict__ Wtq,   // bf16 [16][64][1024]
    const unsigned short* __restrict__ Wtk,
    const unsigned short* __restrict__ Wtv,
    unsigned short* __restrict__ Qo,          // bf16 [B][H][S][K]
    unsigned short* __restrict__ Ko,          // bf16 [B][H][S][K]
    unsigned short* __restrict__ Vto)         // bf16 [B][H][K][S] (permuted)
{
    __shared__ unsigned short xs[2][128 * 64];    // 32KB [m][k] linear, swz
    __shared__ unsigned short ws[2][3][64 * 64];  // 48KB [n][k] per W, swz

    const int h = blockIdx.x, mt = blockIdx.y;
    const int tid = threadIdx.x;
    const int wv = tid >> 6, lane = tid & 63;
    const int wm = wv & 3, wn = wv >> 2;      // 4 m-groups x 2 n-halves
    const int quad = lane >> 4, l15 = lane & 15;
    const int l8 = lane >> 3;
    const int c8 = ((lane & 7) ^ l8) * 8;   // pre-swizzled source col (elems)
    const int x7 = l15 & 7;                 // read-side XOR key
    const int m0 = mt * 128;

    const unsigned short* wsrc[3] = {
        Wtq + (size_t)h * 65536, Wtk + (size_t)h * 65536, Wtv + (size_t)h * 65536 };

    f32x4 acc[3][2][2] = {};   // [w][mfrag][nbh]

    auto stage = [&](int bi, int k0) {
        // xs: 128 rows, 16 issues = 2/wave (rows wv*16 + j*8 + l8)
        const unsigned short* xg =
            xb + (size_t)(m0 + wv * 16 + l8) * 1024 + k0 + c8;
        #pragma unroll
        for (int j = 0; j < 2; ++j)
            gl_lds16(xg + (size_t)j * 8 * 1024, &xs[bi][(wv * 2 + j) * 512]);
        // ws: 3 x 64 rows, 24 issues = 3/wave (flat = wv*3+i: w=flat>>3, rb=flat&7)
        #pragma unroll
        for (int i = 0; i < 3; ++i) {
            const int flat = wv * 3 + i;
            const int w = flat >> 3, rb = flat & 7;
            gl_lds16(wsrc[w] + (size_t)(rb * 8 + l8) * 1024 + k0 + c8,
                     &ws[bi][w][rb * 512]);
        }
    };

    stage(0, 0);
    __syncthreads();   // compiler emits vmcnt(0) drain here

    for (int kt = 0; kt < 16; ++kt) {
        const int cur = kt & 1;
        if (kt < 15) stage(cur ^ 1, (kt + 1) * 64);   // prefetch next tile

        const unsigned short* xsc = xs[cur];
        #pragma unroll
        for (int kh = 0; kh < 2; ++kh) {
            const int csw = ((kh * 4 + quad) ^ x7) * 8;   // rows used have r&7==x7
            const bf16x8 a0 = *(const bf16x8*)&xsc[(wm * 32 + l15) * 64 + csw];
            const bf16x8 a1 = *(const bf16x8*)&xsc[(wm * 32 + 16 + l15) * 64 + csw];
            #pragma unroll
            for (int nbh = 0; nbh < 2; ++nbh) {
                const int nb = wn * 2 + nbh;
                #pragma unroll
                for (int w = 0; w < 3; ++w) {
                    const bf16x8 bfr = *(const bf16x8*)&ws[cur][w][(nb * 16 + l15) * 64 + csw];
                    acc[w][0][nbh] = __builtin_amdgcn_mfma_f32_16x16x32_bf16(a0, bfr, acc[w][0][nbh], 0, 0, 0);
                    acc[w][1][nbh] = __builtin_amdgcn_mfma_f32_16x16x32_bf16(a1, bfr, acc[w][1][nbh], 0, 0, 0);
                }
            }
        }
        __syncthreads();   // drains this iter's prefetch (issued pre-compute)
    }

    // Q (scaled), K epilogue: C row = quad*4+reg, col = l15. [B][H][S][K]
    #pragma unroll
    for (int mf = 0; mf < 2; ++mf)
        #pragma unroll
        for (int r = 0; r < 4; ++r) {
            const int s  = m0 + wm * 32 + mf * 16 + quad * 4 + r;
            const int bb = s >> 11;
            const int ss = s & (S_ - 1);
            const size_t base = (((size_t)(bb * H_ + h)) * S_ + ss) * K_;
            #pragma unroll
            for (int nbh = 0; nbh < 2; ++nbh) {
                const int nb = wn * 2 + nbh;
                Qo[base + nb * 16 + l15] = f2b(acc[0][mf][nbh][r] * QSCALE);
                Ko[base + nb * 16 + l15] = f2b(acc[1][mf][nbh][r]);
            }
        }

    // V epilogue: transposed + k-permuted (kappa = quad*8 + mf*4 + r), 8B store
    {
        const int sb32 = m0 + wm * 32;           // 32-aligned block base
        const int bb   = sb32 >> 11;
        const int ssb  = sb32 & (S_ - 1);        // 32-aligned
        #pragma unroll
        for (int mf = 0; mf < 2; ++mf) {
            const int kap = quad * 8 + mf * 4;   // permuted offset in 32-block
            #pragma unroll
            for (int nbh = 0; nbh < 2; ++nbh) {
                const int k = (wn * 2 + nbh) * 16 + l15;
                const size_t vaddr = (((size_t)(bb * H_ + h)) * K_ + k) * S_ + ssb + kap;
                uint2 u;
                u.x = (unsigned int)f2b(acc[2][mf][nbh][0]) | ((unsigned int)f2b(acc[2][mf][nbh][1]) << 16);
                u.y = (unsigned int)f2b(acc[2][mf][nbh][2]) | ((unsigned int)f2b(acc[2][mf][nbh][3]) << 16);
                *(uint2*)&Vto[vaddr] = u;
            }
        }
    }
}

// ===========================================================================
// Kernel B (MFMA flash attention v9, unchanged from R6 — 49.7us, Mfma 27.8):
// 128t per barrier period (2 sub-tiles, dbuf), P-in-registers via Vtp
// k-permuted layout, deferred li reduction, XCD swizzle, p=2^s.
// ===========================================================================
__global__ __launch_bounds__(256) void attn_mfma2(
    const unsigned short* __restrict__ Qb,
    const unsigned short* __restrict__ Kb,
    const unsigned short* __restrict__ Vt,   // [B][H][K][S] permuted
    unsigned short* __restrict__ Cb)         // [B][S][H][K]
{
    __shared__ unsigned short ks[2][2][64 * 64];  // [buf][half] K [t][k] swz
    __shared__ unsigned short vs[2][2][64 * 64];  // [buf][half] Vtp [d][kap]

    // XCD-aware bijective swizzle: nwg=512, 8 XCDs, chunk=64 (= 4 full bh).
    const int bid = blockIdx.x;
    const int lid = (bid & 7) * 64 + (bid >> 3);
    const int qt  = lid & 15;
    const int bh  = lid >> 4;
    const int h   = bh & 15;
    const int b   = bh >> 4;

    const int tid  = threadIdx.x;
    const int wv = tid >> 6, lane = tid & 63;
    const int quad = lane >> 4, l15 = lane & 15;
    const int l8 = lane >> 3;
    const int c8 = ((lane & 7) ^ l8) * 8;
    const int x7 = l15 & 7;

    const size_t base = ((size_t)(b * H_ + h)) * S_ * K_;   // Q,K and Vt extent

    // Q fragments: wave owns 32 q-rows = 2 groups of 16 (B-op of swapped QK^T)
    bf16x8 qf[2][2];
    #pragma unroll
    for (int g = 0; g < 2; ++g) {
        const int qrow = qt * 128 + wv * 32 + g * 16 + l15;
        qf[g][0] = *(const bf16x8*)(Qb + base + (size_t)qrow * K_ + quad * 8);
        qf[g][1] = *(const bf16x8*)(Qb + base + (size_t)qrow * K_ + 32 + quad * 8);
    }

    f32x4 ctxa[2][4] = {};
    float li[2] = {0.0f, 0.0f};   // PER-QUAD partial row-sum (reduced at end)

    auto stage = [&](int bi, int t0) {
        #pragma unroll
        for (int hf = 0; hf < 2; ++hf) {
            const unsigned short* kg =
                Kb + base + (size_t)(t0 + hf * 64 + wv * 16 + l8) * K_ + c8;
            gl_lds16(kg,          &ks[bi][hf][(wv * 2 + 0) * 512]);
            gl_lds16(kg + 8 * K_, &ks[bi][hf][(wv * 2 + 1) * 512]);
            const unsigned short* vg =
                Vt + base + (size_t)(wv * 16 + l8) * S_ + t0 + hf * 64 + c8;
            gl_lds16(vg,          &vs[bi][hf][(wv * 2 + 0) * 512]);
            gl_lds16(vg + 8 * S_, &vs[bi][hf][(wv * 2 + 1) * 512]);
        }
    };

    stage(0, 0);
    __syncthreads();   // vmcnt(0) drain of prologue stage

    for (int it = 0; it < S_ / 128; ++it) {
        const int cur = it & 1;
        if (it < S_ / 128 - 1) stage(cur ^ 1, (it + 1) * 128);   // prefetch

        #pragma unroll
        for (int hf = 0; hf < 2; ++hf) {
            const unsigned short* ksc = ks[cur][hf];
            const unsigned short* vsc = vs[cur][hf];

            // ---- S^T = K.Q^T : lane holds S[t=16tb+quad*4+r][q=l15] ----
            f32x4 sac[2][4] = {};
            __builtin_amdgcn_s_setprio(1);
            #pragma unroll
            for (int tb = 0; tb < 4; ++tb) {
                const bf16x8 kf0 = *(const bf16x8*)&ksc[(tb * 16 + l15) * 64 + ((quad) ^ x7) * 8];
                const bf16x8 kf1 = *(const bf16x8*)&ksc[(tb * 16 + l15) * 64 + ((4 + quad) ^ x7) * 8];
                #pragma unroll
                for (int g = 0; g < 2; ++g) {
                    sac[g][tb] = __builtin_amdgcn_mfma_f32_16x16x32_bf16(kf0, qf[g][0], sac[g][tb], 0, 0, 0);
                    sac[g][tb] = __builtin_amdgcn_mfma_f32_16x16x32_bf16(kf1, qf[g][1], sac[g][tb], 0, 0, 0);
                }
            }
            __builtin_amdgcn_s_setprio(0);

            // ---- softmax: p = 2^s; in-lane partial sum; pack A-frags ----
            bf16x8 pa[2][2];   // [g][kh] PV A-operand, fully lane-local
            #pragma unroll
            for (int g = 0; g < 2; ++g) {
                float ps[4][4];
                float rs = 0.0f;
                #pragma unroll
                for (int tb = 0; tb < 4; ++tb)
                    #pragma unroll
                    for (int r = 0; r < 4; ++r) {
                        const float p = fexp2(sac[g][tb][r]);
                        ps[tb][r] = p;
                        rs += p;
                    }
                li[g] += rs;   // per-quad partial; cross-quad reduce deferred

                #pragma unroll
                for (int kh = 0; kh < 2; ++kh) {
                    union { bf16x8 v; unsigned short s[8]; } u;
                    u.s[0] = f2b(ps[2 * kh][0]);     u.s[1] = f2b(ps[2 * kh][1]);
                    u.s[2] = f2b(ps[2 * kh][2]);     u.s[3] = f2b(ps[2 * kh][3]);
                    u.s[4] = f2b(ps[2 * kh + 1][0]); u.s[5] = f2b(ps[2 * kh + 1][1]);
                    u.s[6] = f2b(ps[2 * kh + 1][2]); u.s[7] = f2b(ps[2 * kh + 1][3]);
                    pa[g][kh] = u.v;
                }
            }

            // ---- PV: ctx[q][d], A = pa (regs), B = Vtp rows ----
            __builtin_amdgcn_s_setprio(1);
            #pragma unroll
            for (int kh = 0; kh < 2; ++kh)
                #pragma unroll
                for (int cb = 0; cb < 4; ++cb) {
                    const bf16x8 bfr = *(const bf16x8*)&vsc[(cb * 16 + l15) * 64 + ((kh * 4 + quad) ^ x7) * 8];
                    #pragma unroll
                    for (int g = 0; g < 2; ++g)
                        ctxa[g][cb] = __builtin_amdgcn_mfma_f32_16x16x32_bf16(pa[g][kh], bfr, ctxa[g][cb], 0, 0, 0);
                }
            __builtin_amdgcn_s_setprio(0);
        }

        __syncthreads();   // drains this iter's prefetch; protects buf reuse
    }

    // ---- epilogue: reduce li across quads ONCE, normalize, write ----
    #pragma unroll
    for (int g = 0; g < 2; ++g) {
        float lf = li[g];
        lf += __shfl_xor(lf, 16);
        lf += __shfl_xor(lf, 32);
        #pragma unroll
        for (int r = 0; r < 4; ++r) {
            const float inv = 1.0f / __shfl(lf, quad * 4 + r);
            const int s = qt * 128 + wv * 32 + g * 16 + quad * 4 + r;
            const size_t ob = (((size_t)(b * S_ + s)) * H_ + h) * K_;
            #pragma unroll
            for (int cb = 0; cb < 4; ++cb)
                Cb[ob + cb * 16 + l15] = f2b(ctxa[g][cb][r] * inv);
        }
    }
}

// ===========================================================================
// Fallback attention (R5-verified): reads V [B][H][S][K], in-kernel
// transpose, running-max softmax. (Expects UNSCALED Q from qkv_proj.)
// ===========================================================================
__global__ __launch_bounds__(256) void attn_mfma_v1(
    const unsigned short* __restrict__ Qb,
    const unsigned short* __restrict__ Kb,
    const unsigned short* __restrict__ Vb,
    unsigned short* __restrict__ Cb)
{
    __shared__ unsigned short ks[64 * 72];
    __shared__ unsigned short vt[64 * 72];
    __shared__ unsigned short pbuf[4 * 16 * 72];

    const int b = blockIdx.z, h = blockIdx.y, qt = blockIdx.x;
    const int tid  = threadIdx.x;
    const int wave = tid >> 6, lane = tid & 63;
    const int quad = lane >> 4, l15 = lane & 15;

    const size_t base = ((size_t)(b * H_ + h)) * S_ * K_;

    const int qrow = qt * 64 + wave * 16 + l15;
    const bf16x8 qf0 = *(const bf16x8*)(Qb + base + (size_t)qrow * K_ + quad * 8);
    const bf16x8 qf1 = *(const bf16x8*)(Qb + base + (size_t)qrow * K_ + 32 + quad * 8);

    f32x4 ctxa[4] = {};
    float mi[4], li[4];
    #pragma unroll
    for (int r = 0; r < 4; ++r) { mi[r] = -INFINITY; li[r] = 0.0f; }

    unsigned short* pw = pbuf + wave * 16 * 72;

    for (int tb0 = 0; tb0 < S_; tb0 += 64) {
        __syncthreads();
        #pragma unroll
        for (int p = 0; p < 2; ++p) {
            const int idx = tid + p * 256;
            const int t = idx >> 3, c = idx & 7;
            *(uint4*)&ks[t * 72 + c * 8] =
                *(const uint4*)(Kb + base + (size_t)(tb0 + t) * K_ + c * 8);
        }
        #pragma unroll
        for (int p = 0; p < 2; ++p) {
            const int c = wave + p * 4;
            uint4 u = *(const uint4*)(Vb + base + (size_t)(tb0 + lane) * K_ + c * 8);
            const unsigned short* us = (const unsigned short*)&u;
            #pragma unroll
            for (int d = 0; d < 8; ++d)
                vt[(c * 8 + d) * 72 + lane] = us[d];
        }
        __syncthreads();

        f32x4 sac[4] = {};
        #pragma unroll
        for (int tb = 0; tb < 4; ++tb) {
            const bf16x8 kf0 = *(const bf16x8*)&ks[(tb * 16 + l15) * 72 + quad * 8];
            const bf16x8 kf1 = *(const bf16x8*)&ks[(tb * 16 + l15) * 72 + 32 + quad * 8];
            sac[tb] = __builtin_amdgcn_mfma_f32_16x16x32_bf16(qf0, kf0, sac[tb], 0, 0, 0);
            sac[tb] = __builtin_amdgcn_mfma_f32_16x16x32_bf16(qf1, kf1, sac[tb], 0, 0, 0);
        }

        float mnew[4], alpha[4];
        #pragma unroll
        for (int r = 0; r < 4; ++r) {
            float v = fmaxf(fmaxf(sac[0][r], sac[1][r]), fmaxf(sac[2][r], sac[3][r])) * 0.125f;
            v = fmaxf(v, __shfl_xor(v, 1));
            v = fmaxf(v, __shfl_xor(v, 2));
            v = fmaxf(v, __shfl_xor(v, 4));
            v = fmaxf(v, __shfl_xor(v, 8));
            mnew[r]  = fmaxf(mi[r], v);
            alpha[r] = __expf(mi[r] - mnew[r]);
            mi[r]    = mnew[r];
        }
        float pv[4][4], rs[4];
        #pragma unroll
        for (int r = 0; r < 4; ++r) rs[r] = 0.0f;
        #pragma unroll
        for (int tb = 0; tb < 4; ++tb)
            #pragma unroll
            for (int r = 0; r < 4; ++r) {
                const float p = __expf(sac[tb][r] * 0.125f - mnew[r]);
                pv[tb][r] = p;
                rs[r] += p;
            }
        #pragma unroll
        for (int r = 0; r < 4; ++r) {
            float s = rs[r];
            s += __shfl_xor(s, 1);
            s += __shfl_xor(s, 2);
            s += __shfl_xor(s, 4);
            s += __shfl_xor(s, 8);
            li[r] = li[r] * alpha[r] + s;
        }
        #pragma unroll
        for (int cb = 0; cb < 4; ++cb)
            #pragma unroll
            for (int r = 0; r < 4; ++r)
                ctxa[cb][r] *= alpha[r];

        #pragma unroll
        for (int tb = 0; tb < 4; ++tb)
            #pragma unroll
            for (int r = 0; r < 4; ++r)
                pw[(quad * 4 + r) * 72 + tb * 16 + l15] = f2b(pv[tb][r]);

        #pragma unroll
        for (int kh = 0; kh < 2; ++kh) {
            const bf16x8 af = *(const bf16x8*)&pw[l15 * 72 + kh * 32 + quad * 8];
            #pragma unroll
            for (int cb = 0; cb < 4; ++cb) {
                const bf16x8 bfr = *(const bf16x8*)&vt[(cb * 16 + l15) * 72 + kh * 32 + quad * 8];
                ctxa[cb] = __builtin_amdgcn_mfma_f32_16x16x32_bf16(af, bfr, ctxa[cb], 0, 0, 0);
            }
        }
    }

    #pragma unroll
    for (int r = 0; r < 4; ++r) {
        const float inv = 1.0f / li[r];
        const int s = qt * 64 + wave * 16 + quad * 4 + r;
        const size_t ob = (((size_t)(b * S_ + s)) * H_ + h) * K_;
        #pragma unroll
        for (int cb = 0; cb < 4; ++cb)
            Cb[ob + cb * 16 + l15] = f2b(ctxa[cb][r] * inv);
    }
}

// ===========================================================================
// Kernel C (MFMA): output projection + head sum — R7: 512 threads, 8 waves
// (4 m-groups x 2 n-halves), 16 waves/CU (was 8).
// ===========================================================================
__global__ __launch_bounds__(512, 4) void gemm_out(
    const unsigned short* __restrict__ ctx,   // bf16 [4096][1024]
    const unsigned short* __restrict__ Wot,   // bf16 [1024 d][1024 hk]
    float* __restrict__ out)                  // fp32 [4096][1024]
{
    __shared__ unsigned short cs[2][128 * 64];   // 32KB
    __shared__ unsigned short ws[2][64 * 64];    // 16KB

    const int nt = blockIdx.x, mt = blockIdx.y;
    const int tid = threadIdx.x;
    const int wv = tid >> 6, lane = tid & 63;
    const int wm = wv & 3, wn = wv >> 2;
    const int quad = lane >> 4, l15 = lane & 15;
    const int l8 = lane >> 3;
    const int c8 = ((lane & 7) ^ l8) * 8;
    const int x7 = l15 & 7;
    const int m0 = mt * 128, n0 = nt * 64;

    f32x4 acc[2][2] = {};   // [mfrag][nbh]

    auto stage = [&](int bi, int k0) {
        // cs: 128 rows, 16 issues = 2/wave
        const unsigned short* cg =
            ctx + (size_t)(m0 + wv * 16 + l8) * 1024 + k0 + c8;
        #pragma unroll
        for (int j = 0; j < 2; ++j)
            gl_lds16(cg + (size_t)j * 8 * 1024, &cs[bi][(wv * 2 + j) * 512]);
        // ws: 64 rows, 8 issues = 1/wave
        gl_lds16(Wot + (size_t)(n0 + wv * 8 + l8) * 1024 + k0 + c8,
                 &ws[bi][wv * 512]);
    };

    stage(0, 0);
    __syncthreads();

    for (int kt = 0; kt < 16; ++kt) {
        const int cur = kt & 1;
        if (kt < 15) stage(cur ^ 1, (kt + 1) * 64);

        const unsigned short* csc = cs[cur];
        const unsigned short* wsc = ws[cur];
        #pragma unroll
        for (int kh = 0; kh < 2; ++kh) {
            const int csw = ((kh * 4 + quad) ^ x7) * 8;
            const bf16x8 a0 = *(const bf16x8*)&csc[(wm * 32 + l15) * 64 + csw];
            const bf16x8 a1 = *(const bf16x8*)&csc[(wm * 32 + 16 + l15) * 64 + csw];
            #pragma unroll
            for (int nbh = 0; nbh < 2; ++nbh) {
                const int nb = wn * 2 + nbh;
                const bf16x8 bfr = *(const bf16x8*)&wsc[(nb * 16 + l15) * 64 + csw];
                acc[0][nbh] = __builtin_amdgcn_mfma_f32_16x16x32_bf16(a0, bfr, acc[0][nbh], 0, 0, 0);
                acc[1][nbh] = __builtin_amdgcn_mfma_f32_16x16x32_bf16(a1, bfr, acc[1][nbh], 0, 0, 0);
            }
        }
        __syncthreads();
    }

    #pragma unroll
    for (int mf = 0; mf < 2; ++mf)
        #pragma unroll
        for (int r = 0; r < 4; ++r) {
            const int m = m0 + wm * 32 + mf * 16 + quad * 4 + r;
            #pragma unroll
            for (int nbh = 0; nbh < 2; ++nbh) {
                const int nb = wn * 2 + nbh;
                out[(size_t)m * 1024 + n0 + nb * 16 + l15] = acc[mf][nbh][r];
            }
        }
}

// ===========================================================================
// FALLBACK (32 MB ws): fp32 VALU projections (R5-verified)
// ===========================================================================
__global__ __launch_bounds__(256) void qkv_proj(
    const float* __restrict__ x, const float* __restrict__ Wq,
    const float* __restrict__ Wk, const float* __restrict__ Wv,
    unsigned short* __restrict__ Qo, unsigned short* __restrict__ Ko,
    unsigned short* __restrict__ Vo)
{
    __shared__ float xs[32][68];
    __shared__ float wqs[32][68];
    __shared__ float wks[32][68];
    __shared__ float wvs[32][68];

    const int h  = blockIdx.x;
    const int m0 = blockIdx.y * 64;
    const int t  = threadIdx.x;
    const int tx = t & 15, ty = t >> 4;
    const int xr = t >> 2, xc = (t & 3) * 8;
    const int wr = t >> 3, wc = (t & 7) * 8;

    float aq[4][4] = {}, ak[4][4] = {}, av[4][4] = {};
    const int wbase = h * D_ * K_;

    for (int d0 = 0; d0 < D_; d0 += 32) {
        __syncthreads();
        {
            const float* xf = x + (size_t)(m0 + xr) * D_ + d0 + xc;
            const float4 a = *(const float4*)xf;
            const float4 b = *(const float4*)(xf + 4);
            xs[xc + 0][xr] = a.x; xs[xc + 1][xr] = a.y;
            xs[xc + 2][xr] = a.z; xs[xc + 3][xr] = a.w;
            xs[xc + 4][xr] = b.x; xs[xc + 5][xr] = b.y;
            xs[xc + 6][xr] = b.z; xs[xc + 7][xr] = b.w;
        }
        {
            const size_t idx = (size_t)wbase + (size_t)(d0 + wr) * K_ + wc;
            *(float4*)&wqs[wr][wc]     = *(const float4*)&Wq[idx];
            *(float4*)&wqs[wr][wc + 4] = *(const float4*)&Wq[idx + 4];
            *(float4*)&wks[wr][wc]     = *(const float4*)&Wk[idx];
            *(float4*)&wks[wr][wc + 4] = *(const float4*)&Wk[idx + 4];
            *(float4*)&wvs[wr][wc]     = *(const float4*)&Wv[idx];
            *(float4*)&wvs[wr][wc + 4] = *(const float4*)&Wv[idx + 4];
        }
        __syncthreads();

        #pragma unroll 8
        for (int kk = 0; kk < 32; ++kk) {
            const float4 xv = *(const float4*)&xs[kk][ty * 4];
            const float4 q4 = *(const float4*)&wqs[kk][tx * 4];
            const float4 k4 = *(const float4*)&wks[kk][tx * 4];
            const float4 v4 = *(const float4*)&wvs[kk][tx * 4];
            const float xa[4] = {xv.x, xv.y, xv.z, xv.w};
            const float qa[4] = {q4.x, q4.y, q4.z, q4.w};
            const float ka[4] = {k4.x, k4.y, k4.z, k4.w};
            const float va[4] = {v4.x, v4.y, v4.z, v4.w};
            #pragma unroll
            for (int i = 0; i < 4; ++i)
                #pragma unroll
                for (int j = 0; j < 4; ++j) {
                    aq[i][j] += xa[i] * qa[j];
                    ak[i][j] += xa[i] * ka[j];
                    av[i][j] += xa[i] * va[j];
                }
        }
    }

    #pragma unroll
    for (int i = 0; i < 4; ++i) {
        const int m  = m0 + ty * 4 + i;
        const int bb = m >> 11;
        const int ss = m & (S_ - 1);
        const size_t base = (((size_t)(bb * H_ + h)) * S_ + ss) * K_ + tx * 4;
        ushort4 pq, pk, pv;
        pq.x = f2b(aq[i][0]); pq.y = f2b(aq[i][1]); pq.z = f2b(aq[i][2]); pq.w = f2b(aq[i][3]);
        pk.x = f2b(ak[i][0]); pk.y = f2b(ak[i][1]); pk.z = f2b(ak[i][2]); pk.w = f2b(ak[i][3]);
        pv.x = f2b(av[i][0]); pv.y = f2b(av[i][1]); pv.z = f2b(av[i][2]); pv.w = f2b(av[i][3]);
        *(ushort4*)&Qo[base] = pq;
        *(ushort4*)&Ko[base] = pk;
        *(ushort4*)&Vo[base] = pv;
    }
}

__global__ __launch_bounds__(256) void out_proj(
    const unsigned int* __restrict__ Cb, const float* __restrict__ Wo,
    float* __restrict__ out)
{
    __shared__ float cs[32][68];
    __shared__ float wos[32][68];

    const int n0 = blockIdx.x * 64;
    const int m0 = blockIdx.y * 64;
    const int t  = threadIdx.x;
    const int tx = t & 15, ty = t >> 4;
    const int xr = t >> 2, xc = (t & 3) * 8;
    const int wr = t >> 3, wc = (t & 7) * 8;

    float acc[4][4] = {};

    for (int k0 = 0; k0 < 1024; k0 += 32) {
        __syncthreads();
        {
            uint4 u = *(const uint4*)&Cb[((size_t)(m0 + xr) * 1024 + k0 + xc) >> 1];
            cs[xc + 0][xr] = bf_lo(u.x); cs[xc + 1][xr] = bf_hi(u.x);
            cs[xc + 2][xr] = bf_lo(u.y); cs[xc + 3][xr] = bf_hi(u.y);
            cs[xc + 4][xr] = bf_lo(u.z); cs[xc + 5][xr] = bf_hi(u.z);
            cs[xc + 6][xr] = bf_lo(u.w); cs[xc + 7][xr] = bf_hi(u.w);
        }
        {
            const float* wof = Wo + (size_t)(k0 + wr) * 1024 + n0 + wc;
            *(float4*)&wos[wr][wc]     = *(const float4*)wof;
            *(float4*)&wos[wr][wc + 4] = *(const float4*)(wof + 4);
        }
        __syncthreads();

        #pragma unroll 8
        for (int kk = 0; kk < 32; ++kk) {
            const float4 cv = *(const float4*)&cs[kk][ty * 4];
            const float4 wv = *(const float4*)&wos[kk][tx * 4];
            const float ca[4] = {cv.x, cv.y, cv.z, cv.w};
            const float wa[4] = {wv.x, wv.y, wv.z, wv.w};
            #pragma unroll
            for (int i = 0; i < 4; ++i)
                #pragma unroll
                for (int j = 0; j < 4; ++j)
                    acc[i][j] += ca[i] * wa[j];
        }
    }

    #pragma unroll
    for (int i = 0; i < 4; ++i) {
        const int m = m0 + ty * 4 + i;
        float4 p = make_float4(acc[i][0], acc[i][1], acc[i][2], acc[i][3]);
        *(float4*)&out[(size_t)m * 1024 + n0 + tx * 4] = p;
    }
}

// ===========================================================================
extern "C" void kernel_launch(void* const* d_in, const int* in_sizes, int n_in,
                              void* d_out, int out_size, void* d_ws, size_t ws_size,
                              hipStream_t stream)
{
    (void)in_sizes; (void)n_in; (void)out_size;
    const float* x  = (const float*)d_in[0];
    const float* Wq = (const float*)d_in[1];
    const float* Wk = (const float*)d_in[2];
    const float* Wv = (const float*)d_in[3];
    const float* Wo = (const float*)d_in[4];
    float* out = (float*)d_out;

    const size_t QKV_ELEMS = (size_t)B_ * H_ * S_ * K_;   // 4,194,304

    if (ws_size >= (size_t)40 * 1024 * 1024) {
        // ws layout (bf16 elems), exactly 40 MB:
        //  xb (8MB; aliased by ctx after gemm_qkv) | Wtq|Wtk|Wtv (2MB each) |
        //  Wot (2MB) | Q (8MB) | K (8MB) | Vt (8MB, [B][H][K][S] permuted)
        unsigned short* xb  = (unsigned short*)d_ws;
        unsigned short* Wtq = xb  + (size_t)4096 * 1024;
        unsigned short* Wtk = Wtq + (size_t)16 * 64 * 1024;
        unsigned short* Wtv = Wtk + (size_t)16 * 64 * 1024;
        unsigned short* Wot = Wtv + (size_t)16 * 64 * 1024;
        unsigned short* Qb  = Wot + (size_t)1024 * 1024;
        unsigned short* Kb  = Qb + QKV_ELEMS;
        unsigned short* Vtb = Kb + QKV_ELEMS;
        unsigned short* Cb  = xb;   // alias: xb dead after gemm_qkv

        prep_all<<<dim3(5120), 256, 0, stream>>>(
            x, Wq, Wk, Wv, Wo, xb, Wtq, Wtk, Wtv, Wot);

        gemm_qkv<<<dim3(16, 32), 512, 0, stream>>>(xb, Wtq, Wtk, Wtv, Qb, Kb, Vtb);
        attn_mfma2<<<dim3(512), 256, 0, stream>>>(Qb, Kb, Vtb, Cb);
        gemm_out<<<dim3(16, 32), 512, 0, stream>>>(Cb, Wot, out);
    } else {
        // fallback (32 MB): Q | K | V | ctx   (R5-verified path)
        unsigned short* Qb = (unsigned short*)d_ws;
        unsigned short* Kb = Qb + QKV_ELEMS;
        unsigned short* Vb = Kb + QKV_ELEMS;
        unsigned short* Cb = Vb + QKV_ELEMS;

        qkv_proj<<<dim3(16, 64), 256, 0, stream>>>(x, Wq, Wk, Wv, Qb, Kb, Vb);
        attn_mfma_v1<<<dim3(32, 16, 2), 256, 0, stream>>>(Qb, Kb, Vb, Cb);
        out_proj<<<dim3(16, 64), 256, 0, stream>>>((const unsigned int*)Cb, Wo, out);
    }
}

// Round 8
// 167.796 us; speedup vs baseline: 1.1011x; 1.0064x over previous
//
#include <hip/hip_runtime.h>
#include <hip/hip_bf16.h>

// Shapes (fixed by reference): B=2, S=2048, D=1024, H=16, K(d_head)=64
// Inputs FP32, output FP32. Intermediates bf16 in d_ws (40 MB layout).
#define B_ 2
#define S_ 2048
#define D_ 1024
#define H_ 16
#define K_ 64
// BS = 4096, HK = 1024

// softmax scale folded into Q at projection time: 0.125 * log2(e)
#define QSCALE 0.18033688f

typedef __attribute__((ext_vector_type(4))) float f32x4;
typedef __attribute__((ext_vector_type(8))) short bf16x8;

__device__ __forceinline__ float bf_lo(unsigned int u) {
    union { float f; unsigned int i; } c; c.i = u << 16; return c.f;
}
__device__ __forceinline__ float bf_hi(unsigned int u) {
    union { float f; unsigned int i; } c; c.i = u & 0xffff0000u; return c.f;
}
__device__ __forceinline__ unsigned short f2b(float f) {
    __hip_bfloat16 h = __float2bfloat16(f);   // RNE
    union { __hip_bfloat16 h; unsigned short s; } c; c.h = h; return c.s;
}

// 2^x via v_exp_f32 (scale pre-folded into Q upstream)
__device__ __forceinline__ float fexp2(float x) {
#if __has_builtin(__builtin_amdgcn_exp2f)
    return __builtin_amdgcn_exp2f(x);
#else
    float r; asm("v_exp_f32 %0, %1" : "=v"(r) : "v"(x)); return r;
#endif
}

// Direct global->LDS, 16B per lane. LDS dest is wave-uniform base + lane*16
// (linear).
__device__ __forceinline__ void gl_lds16(const unsigned short* g, const unsigned short* l)
{
    __builtin_amdgcn_global_load_lds(
        (const __attribute__((address_space(1))) unsigned int*)(unsigned long long)g,
        (__attribute__((address_space(3))) unsigned int*)(unsigned int)(unsigned long long)l,
        16, 0, 0);
}

// ===========================================================================
// PREP (merged, FLAT grid):
// blocks [0,4096):   x -> bf16 cvt (4 elems/thread)
// blocks [4096,4864): Wqkv transpose: mat = (bz-4096)>>4, r0 = ((bz-4096)&15)*64
// blocks [4864,5120): Wo transpose: zz = bz-4864, c0 = (zz&15)*64, r0=(zz>>4)*64
// ===========================================================================
__global__ __launch_bounds__(256) void prep_all(
    const float* __restrict__ x,  const float* __restrict__ Wq,
    const float* __restrict__ Wk, const float* __restrict__ Wv,
    const float* __restrict__ Wo,
    unsigned short* __restrict__ xb,
    unsigned short* __restrict__ Wtq, unsigned short* __restrict__ Wtk,
    unsigned short* __restrict__ Wtv, unsigned short* __restrict__ Wot)
{
    const int bz = blockIdx.x;
    const int t = threadIdx.x;

    if (bz < 4096) {   // ---- cvt x -> bf16 ----
        const int i = (bz * 256 + t) * 4;
        const float4 v = *(const float4*)(x + i);
        ushort4 o;
        o.x = f2b(v.x); o.y = f2b(v.y); o.z = f2b(v.z); o.w = f2b(v.w);
        *(ushort4*)(xb + i) = o;
        return;
    }

    const float* in;
    unsigned short* out;
    int C, c0, r0;
    size_t mb;
    if (bz < 4864) {   // Wqkv: [1024][64] -> [64][1024], 16 r-blocks per mat
        const int zz = bz - 4096;
        const int mat = zz >> 4;           // 0..47
        const int src = mat >> 4, m = mat & 15;
        in  = (src == 0) ? Wq : (src == 1) ? Wk : Wv;
        out = (src == 0) ? Wtq : (src == 1) ? Wtk : Wtv;
        C = 64; c0 = 0; r0 = (zz & 15) * 64;
        mb = (size_t)m * 1024 * 64;
    } else {           // Wo: [1024][1024] -> [1024][1024]^T
        const int zz = bz - 4864;
        in = Wo; out = Wot; C = 1024;
        c0 = (zz & 15) * 64; r0 = (zz >> 4) * 64;
        mb = 0;
    }

    __shared__ float tl[64][65];

    #pragma unroll
    for (int p = 0; p < 4; ++p) {
        const int idx = p * 256 + t;
        const int r = idx >> 4, cc = (idx & 15) * 4;
        const float4 v = *(const float4*)(in + mb + (size_t)(r0 + r) * C + c0 + cc);
        tl[r][cc] = v.x; tl[r][cc + 1] = v.y; tl[r][cc + 2] = v.z; tl[r][cc + 3] = v.w;
    }
    __syncthreads();
    const int c = t >> 2, rc = (t & 3) * 16;
    unsigned int u[8];
    #pragma unroll
    for (int j = 0; j < 8; ++j)
        u[j] = (unsigned int)f2b(tl[rc + 2 * j][c]) |
               ((unsigned int)f2b(tl[rc + 2 * j + 1][c]) << 16);
    unsigned short* op = out + mb + (size_t)(c0 + c) * 1024 + r0 + rc;
    *(uint4*)op       = *(uint4*)&u[0];
    *(uint4*)(op + 8) = *(uint4*)&u[4];
}

// ===========================================================================
// Kernel A (MFMA): fused QKV projection — R8: concatenated single GEMM.
// Wtq|Wtk|Wtv are contiguous in ws => one B matrix [3072 n][1024 k].
// m97-proven structure: 128x128 tile, 256 threads, 4 waves x (64x64 sub-tile,
// 4x4 acc), single-buffered 32KB LDS, 2 barriers/k-step, grid (24,32)=768
// blocks = exactly 3 blocks/CU (12 waves/CU). MFMA:ds_read = 2.0 (was 1.5).
// A 128-wide n-tile never crosses a w boundary; each wave's 64-wide n-range
// is exactly ONE head: h = (nt&7)*2 + wn. Epilogues unchanged in form:
// Q pre-scaled, K direct, V transposed + kappa-permuted (same bijection).
// ===========================================================================
__global__ __launch_bounds__(256, 3) void gemm_qkv(
    const unsigned short* __restrict__ xb,    // bf16 [4096][1024]
    const unsigned short* __restrict__ Wtq,   // bf16 [3072][1024] (concat base)
    const unsigned short* __restrict__ Wtk,   // unused (contiguous with Wtq)
    const unsigned short* __restrict__ Wtv,   // unused
    unsigned short* __restrict__ Qo,          // bf16 [B][H][S][K]
    unsigned short* __restrict__ Ko,          // bf16 [B][H][S][K]
    unsigned short* __restrict__ Vto)         // bf16 [B][H][K][S] (permuted)
{
    (void)Wtk; (void)Wtv;
    __shared__ unsigned short xs[128 * 64];   // A tile [m][k] linear, swz
    __shared__ unsigned short bs[128 * 64];   // B tile [n][k] linear, swz

    const int nt = blockIdx.x, mt = blockIdx.y;
    const int tid = threadIdx.x;
    const int wv = tid >> 6, lane = tid & 63;
    const int wm = wv & 1, wn = wv >> 1;      // 2x2 waves over 128x128
    const int quad = lane >> 4, l15 = lane & 15;
    const int l8 = lane >> 3;
    const int c8 = ((lane & 7) ^ l8) * 8;     // pre-swizzled source col
    const int x7 = l15 & 7;                   // read-side XOR key
    const int m0 = mt * 128, n0 = nt * 128;

    f32x4 acc[4][4] = {};   // [mfrag][nfrag]

    for (int kt = 0; kt < 16; ++kt) {
        const int k0 = kt * 64;
        __syncthreads();   // previous tile's reads complete
        {
            // A: 16 issues / 4 waves = 4 per wave (rows wv*32 + j*8 + l8)
            const unsigned short* ag =
                xb + (size_t)(m0 + wv * 32 + l8) * 1024 + k0 + c8;
            #pragma unroll
            for (int j = 0; j < 4; ++j)
                gl_lds16(ag + (size_t)j * 8 * 1024, &xs[(wv * 4 + j) * 512]);
            // B: same shape from concat weights
            const unsigned short* bg =
                Wtq + (size_t)(n0 + wv * 32 + l8) * 1024 + k0 + c8;
            #pragma unroll
            for (int j = 0; j < 4; ++j)
                gl_lds16(bg + (size_t)j * 8 * 1024, &bs[(wv * 4 + j) * 512]);
        }
        __syncthreads();   // vmcnt(0) drain (2 other resident blocks hide it)

        #pragma unroll
        for (int kh = 0; kh < 2; ++kh) {
            const int csw = ((kh * 4 + quad) ^ x7) * 8;
            bf16x8 af[4], bf[4];
            #pragma unroll
            for (int mf = 0; mf < 4; ++mf)
                af[mf] = *(const bf16x8*)&xs[(wm * 64 + mf * 16 + l15) * 64 + csw];
            #pragma unroll
            for (int nb = 0; nb < 4; ++nb)
                bf[nb] = *(const bf16x8*)&bs[(wn * 64 + nb * 16 + l15) * 64 + csw];
            #pragma unroll
            for (int mf = 0; mf < 4; ++mf)
                #pragma unroll
                for (int nb = 0; nb < 4; ++nb)
                    acc[mf][nb] = __builtin_amdgcn_mfma_f32_16x16x32_bf16(af[mf], bf[nb], acc[mf][nb], 0, 0, 0);
        }
    }

    // ---- epilogue: w = nt>>3 selects Q/K/V; h uniform per wave ----
    const int w = nt >> 3;
    const int h = ((nt & 7) << 1) + wn;       // one head per wave

    if (w < 2) {   // Q (scaled) or K: [B][H][S][K], row=quad*4+r, col c
        unsigned short* outp = (w == 0) ? Qo : Ko;
        const float scale = (w == 0) ? QSCALE : 1.0f;
        #pragma unroll
        for (int mf = 0; mf < 4; ++mf)
            #pragma unroll
            for (int r = 0; r < 4; ++r) {
                const int s  = m0 + wm * 64 + mf * 16 + quad * 4 + r;
                const int bb = s >> 11;
                const int ss = s & (S_ - 1);
                const size_t base = (((size_t)(bb * H_ + h)) * S_ + ss) * K_;
                #pragma unroll
                for (int nb = 0; nb < 4; ++nb)
                    outp[base + nb * 16 + l15] = f2b(acc[mf][nb][r] * scale);
            }
    } else {       // V: transposed + kappa-permuted, 8B stores
        #pragma unroll
        for (int mf = 0; mf < 4; ++mf) {
            const int sb32 = m0 + wm * 64 + (mf >> 1) * 32;   // 32-aligned
            const int bb   = sb32 >> 11;
            const int ssb  = sb32 & (S_ - 1);
            const int kap  = quad * 8 + (mf & 1) * 4;         // permuted pos
            #pragma unroll
            for (int nb = 0; nb < 4; ++nb) {
                const int c = nb * 16 + l15;
                const size_t vaddr = (((size_t)(bb * H_ + h)) * K_ + c) * S_ + ssb + kap;
                uint2 u;
                u.x = (unsigned int)f2b(acc[mf][nb][0]) | ((unsigned int)f2b(acc[mf][nb][1]) << 16);
                u.y = (unsigned int)f2b(acc[mf][nb][2]) | ((unsigned int)f2b(acc[mf][nb][3]) << 16);
                *(uint2*)&Vto[vaddr] = u;
            }
        }
    }
}

// ===========================================================================
// Kernel B (MFMA flash attention v9, unchanged — 49.7us, Mfma 27.8):
// 128t per barrier period (2 sub-tiles, dbuf), P-in-registers via Vtp
// k-permuted layout, deferred li reduction, XCD swizzle, p=2^s.
// ===========================================================================
__global__ __launch_bounds__(256) void attn_mfma2(
    const unsigned short* __restrict__ Qb,
    const unsigned short* __restrict__ Kb,
    const unsigned short* __restrict__ Vt,   // [B][H][K][S] permuted
    unsigned short* __restrict__ Cb)         // [B][S][H][K]
{
    __shared__ unsigned short ks[2][2][64 * 64];  // [buf][half] K [t][k] swz
    __shared__ unsigned short vs[2][2][64 * 64];  // [buf][half] Vtp [d][kap]

    // XCD-aware bijective swizzle: nwg=512, 8 XCDs, chunk=64 (= 4 full bh).
    const int bid = blockIdx.x;
    const int lid = (bid & 7) * 64 + (bid >> 3);
    const int qt  = lid & 15;
    const int bh  = lid >> 4;
    const int h   = bh & 15;
    const int b   = bh >> 4;

    const int tid  = threadIdx.x;
    const int wv = tid >> 6, lane = tid & 63;
    const int quad = lane >> 4, l15 = lane & 15;
    const int l8 = lane >> 3;
    const int c8 = ((lane & 7) ^ l8) * 8;
    const int x7 = l15 & 7;

    const size_t base = ((size_t)(b * H_ + h)) * S_ * K_;   // Q,K and Vt extent

    // Q fragments: wave owns 32 q-rows = 2 groups of 16 (B-op of swapped QK^T)
    bf16x8 qf[2][2];
    #pragma unroll
    for (int g = 0; g < 2; ++g) {
        const int qrow = qt * 128 + wv * 32 + g * 16 + l15;
        qf[g][0] = *(const bf16x8*)(Qb + base + (size_t)qrow * K_ + quad * 8);
        qf[g][1] = *(const bf16x8*)(Qb + base + (size_t)qrow * K_ + 32 + quad * 8);
    }

    f32x4 ctxa[2][4] = {};
    float li[2] = {0.0f, 0.0f};   // PER-QUAD partial row-sum (reduced at end)

    auto stage = [&](int bi, int t0) {
        #pragma unroll
        for (int hf = 0; hf < 2; ++hf) {
            const unsigned short* kg =
                Kb + base + (size_t)(t0 + hf * 64 + wv * 16 + l8) * K_ + c8;
            gl_lds16(kg,          &ks[bi][hf][(wv * 2 + 0) * 512]);
            gl_lds16(kg + 8 * K_, &ks[bi][hf][(wv * 2 + 1) * 512]);
            const unsigned short* vg =
                Vt + base + (size_t)(wv * 16 + l8) * S_ + t0 + hf * 64 + c8;
            gl_lds16(vg,          &vs[bi][hf][(wv * 2 + 0) * 512]);
            gl_lds16(vg + 8 * S_, &vs[bi][hf][(wv * 2 + 1) * 512]);
        }
    };

    stage(0, 0);
    __syncthreads();   // vmcnt(0) drain of prologue stage

    for (int it = 0; it < S_ / 128; ++it) {
        const int cur = it & 1;
        if (it < S_ / 128 - 1) stage(cur ^ 1, (it + 1) * 128);   // prefetch

        #pragma unroll
        for (int hf = 0; hf < 2; ++hf) {
            const unsigned short* ksc = ks[cur][hf];
            const unsigned short* vsc = vs[cur][hf];

            // ---- S^T = K.Q^T : lane holds S[t=16tb+quad*4+r][q=l15] ----
            f32x4 sac[2][4] = {};
            __builtin_amdgcn_s_setprio(1);
            #pragma unroll
            for (int tb = 0; tb < 4; ++tb) {
                const bf16x8 kf0 = *(const bf16x8*)&ksc[(tb * 16 + l15) * 64 + ((quad) ^ x7) * 8];
                const bf16x8 kf1 = *(const bf16x8*)&ksc[(tb * 16 + l15) * 64 + ((4 + quad) ^ x7) * 8];
                #pragma unroll
                for (int g = 0; g < 2; ++g) {
                    sac[g][tb] = __builtin_amdgcn_mfma_f32_16x16x32_bf16(kf0, qf[g][0], sac[g][tb], 0, 0, 0);
                    sac[g][tb] = __builtin_amdgcn_mfma_f32_16x16x32_bf16(kf1, qf[g][1], sac[g][tb], 0, 0, 0);
                }
            }
            __builtin_amdgcn_s_setprio(0);

            // ---- softmax: p = 2^s; in-lane partial sum; pack A-frags ----
            bf16x8 pa[2][2];   // [g][kh] PV A-operand, fully lane-local
            #pragma unroll
            for (int g = 0; g < 2; ++g) {
                float ps[4][4];
                float rs = 0.0f;
                #pragma unroll
                for (int tb = 0; tb < 4; ++tb)
                    #pragma unroll
                    for (int r = 0; r < 4; ++r) {
                        const float p = fexp2(sac[g][tb][r]);
                        ps[tb][r] = p;
                        rs += p;
                    }
                li[g] += rs;   // per-quad partial; cross-quad reduce deferred

                #pragma unroll
                for (int kh = 0; kh < 2; ++kh) {
                    union { bf16x8 v; unsigned short s[8]; } u;
                    u.s[0] = f2b(ps[2 * kh][0]);     u.s[1] = f2b(ps[2 * kh][1]);
                    u.s[2] = f2b(ps[2 * kh][2]);     u.s[3] = f2b(ps[2 * kh][3]);
                    u.s[4] = f2b(ps[2 * kh + 1][0]); u.s[5] = f2b(ps[2 * kh + 1][1]);
                    u.s[6] = f2b(ps[2 * kh + 1][2]); u.s[7] = f2b(ps[2 * kh + 1][3]);
                    pa[g][kh] = u.v;
                }
            }

            // ---- PV: ctx[q][d], A = pa (regs), B = Vtp rows ----
            __builtin_amdgcn_s_setprio(1);
            #pragma unroll
            for (int kh = 0; kh < 2; ++kh)
                #pragma unroll
                for (int cb = 0; cb < 4; ++cb) {
                    const bf16x8 bfr = *(const bf16x8*)&vsc[(cb * 16 + l15) * 64 + ((kh * 4 + quad) ^ x7) * 8];
                    #pragma unroll
                    for (int g = 0; g < 2; ++g)
                        ctxa[g][cb] = __builtin_amdgcn_mfma_f32_16x16x32_bf16(pa[g][kh], bfr, ctxa[g][cb], 0, 0, 0);
                }
            __builtin_amdgcn_s_setprio(0);
        }

        __syncthreads();   // drains this iter's prefetch; protects buf reuse
    }

    // ---- epilogue: reduce li across quads ONCE, normalize, write ----
    #pragma unroll
    for (int g = 0; g < 2; ++g) {
        float lf = li[g];
        lf += __shfl_xor(lf, 16);
        lf += __shfl_xor(lf, 32);
        #pragma unroll
        for (int r = 0; r < 4; ++r) {
            const float inv = 1.0f / __shfl(lf, quad * 4 + r);
            const int s = qt * 128 + wv * 32 + g * 16 + quad * 4 + r;
            const size_t ob = (((size_t)(b * S_ + s)) * H_ + h) * K_;
            #pragma unroll
            for (int cb = 0; cb < 4; ++cb)
                Cb[ob + cb * 16 + l15] = f2b(ctxa[g][cb][r] * inv);
        }
    }
}

// ===========================================================================
// Fallback attention (R5-verified): reads V [B][H][S][K], in-kernel
// transpose, running-max softmax. (Expects UNSCALED Q from qkv_proj.)
// ===========================================================================
__global__ __launch_bounds__(256) void attn_mfma_v1(
    const unsigned short* __restrict__ Qb,
    const unsigned short* __restrict__ Kb,
    const unsigned short* __restrict__ Vb,
    unsigned short* __restrict__ Cb)
{
    __shared__ unsigned short ks[64 * 72];
    __shared__ unsigned short vt[64 * 72];
    __shared__ unsigned short pbuf[4 * 16 * 72];

    const int b = blockIdx.z, h = blockIdx.y, qt = blockIdx.x;
    const int tid  = threadIdx.x;
    const int wave = tid >> 6, lane = tid & 63;
    const int quad = lane >> 4, l15 = lane & 15;

    const size_t base = ((size_t)(b * H_ + h)) * S_ * K_;

    const int qrow = qt * 64 + wave * 16 + l15;
    const bf16x8 qf0 = *(const bf16x8*)(Qb + base + (size_t)qrow * K_ + quad * 8);
    const bf16x8 qf1 = *(const bf16x8*)(Qb + base + (size_t)qrow * K_ + 32 + quad * 8);

    f32x4 ctxa[4] = {};
    float mi[4], li[4];
    #pragma unroll
    for (int r = 0; r < 4; ++r) { mi[r] = -INFINITY; li[r] = 0.0f; }

    unsigned short* pw = pbuf + wave * 16 * 72;

    for (int tb0 = 0; tb0 < S_; tb0 += 64) {
        __syncthreads();
        #pragma unroll
        for (int p = 0; p < 2; ++p) {
            const int idx = tid + p * 256;
            const int t = idx >> 3, c = idx & 7;
            *(uint4*)&ks[t * 72 + c * 8] =
                *(const uint4*)(Kb + base + (size_t)(tb0 + t) * K_ + c * 8);
        }
        #pragma unroll
        for (int p = 0; p < 2; ++p) {
            const int c = wave + p * 4;
            uint4 u = *(const uint4*)(Vb + base + (size_t)(tb0 + lane) * K_ + c * 8);
            const unsigned short* us = (const unsigned short*)&u;
            #pragma unroll
            for (int d = 0; d < 8; ++d)
                vt[(c * 8 + d) * 72 + lane] = us[d];
        }
        __syncthreads();

        f32x4 sac[4] = {};
        #pragma unroll
        for (int tb = 0; tb < 4; ++tb) {
            const bf16x8 kf0 = *(const bf16x8*)&ks[(tb * 16 + l15) * 72 + quad * 8];
            const bf16x8 kf1 = *(const bf16x8*)&ks[(tb * 16 + l15) * 72 + 32 + quad * 8];
            sac[tb] = __builtin_amdgcn_mfma_f32_16x16x32_bf16(qf0, kf0, sac[tb], 0, 0, 0);
            sac[tb] = __builtin_amdgcn_mfma_f32_16x16x32_bf16(qf1, kf1, sac[tb], 0, 0, 0);
        }

        float mnew[4], alpha[4];
        #pragma unroll
        for (int r = 0; r < 4; ++r) {
            float v = fmaxf(fmaxf(sac[0][r], sac[1][r]), fmaxf(sac[2][r], sac[3][r])) * 0.125f;
            v = fmaxf(v, __shfl_xor(v, 1));
            v = fmaxf(v, __shfl_xor(v, 2));
            v = fmaxf(v, __shfl_xor(v, 4));
            v = fmaxf(v, __shfl_xor(v, 8));
            mnew[r]  = fmaxf(mi[r], v);
            alpha[r] = __expf(mi[r] - mnew[r]);
            mi[r]    = mnew[r];
        }
        float pv[4][4], rs[4];
        #pragma unroll
        for (int r = 0; r < 4; ++r) rs[r] = 0.0f;
        #pragma unroll
        for (int tb = 0; tb < 4; ++tb)
            #pragma unroll
            for (int r = 0; r < 4; ++r) {
                const float p = __expf(sac[tb][r] * 0.125f - mnew[r]);
                pv[tb][r] = p;
                rs[r] += p;
            }
        #pragma unroll
        for (int r = 0; r < 4; ++r) {
            float s = rs[r];
            s += __shfl_xor(s, 1);
            s += __shfl_xor(s, 2);
            s += __shfl_xor(s, 4);
            s += __shfl_xor(s, 8);
            li[r] = li[r] * alpha[r] + s;
        }
        #pragma unroll
        for (int cb = 0; cb < 4; ++cb)
            #pragma unroll
            for (int r = 0; r < 4; ++r)
                ctxa[cb][r] *= alpha[r];

        #pragma unroll
        for (int tb = 0; tb < 4; ++tb)
            #pragma unroll
            for (int r = 0; r < 4; ++r)
                pw[(quad * 4 + r) * 72 + tb * 16 + l15] = f2b(pv[tb][r]);

        #pragma unroll
        for (int kh = 0; kh < 2; ++kh) {
            const bf16x8 af = *(const bf16x8*)&pw[l15 * 72 + kh * 32 + quad * 8];
            #pragma unroll
            for (int cb = 0; cb < 4; ++cb) {
                const bf16x8 bfr = *(const bf16x8*)&vt[(cb * 16 + l15) * 72 + kh * 32 + quad * 8];
                ctxa[cb] = __builtin_amdgcn_mfma_f32_16x16x32_bf16(af, bfr, ctxa[cb], 0, 0, 0);
            }
        }
    }

    #pragma unroll
    for (int r = 0; r < 4; ++r) {
        const float inv = 1.0f / li[r];
        const int s = qt * 64 + wave * 16 + quad * 4 + r;
        const size_t ob = (((size_t)(b * S_ + s)) * H_ + h) * K_;
        #pragma unroll
        for (int cb = 0; cb < 4; ++cb)
            Cb[ob + cb * 16 + l15] = f2b(ctxa[cb][r] * inv);
    }
}

// ===========================================================================
// Kernel C (MFMA): output projection + head sum — R7 structure kept:
// 512 threads, 8 waves (4m x 2n halves), dbuf + prefetch, 16 waves/CU.
// ===========================================================================
__global__ __launch_bounds__(512, 4) void gemm_out(
    const unsigned short* __restrict__ ctx,   // bf16 [4096][1024]
    const unsigned short* __restrict__ Wot,   // bf16 [1024 d][1024 hk]
    float* __restrict__ out)                  // fp32 [4096][1024]
{
    __shared__ unsigned short cs[2][128 * 64];   // 32KB
    __shared__ unsigned short ws[2][64 * 64];    // 16KB

    const int nt = blockIdx.x, mt = blockIdx.y;
    const int tid = threadIdx.x;
    const int wv = tid >> 6, lane = tid & 63;
    const int wm = wv & 3, wn = wv >> 2;
    const int quad = lane >> 4, l15 = lane & 15;
    const int l8 = lane >> 3;
    const int c8 = ((lane & 7) ^ l8) * 8;
    const int x7 = l15 & 7;
    const int m0 = mt * 128, n0 = nt * 64;

    f32x4 acc[2][2] = {};   // [mfrag][nbh]

    auto stage = [&](int bi, int k0) {
        // cs: 128 rows, 16 issues = 2/wave
        const unsigned short* cg =
            ctx + (size_t)(m0 + wv * 16 + l8) * 1024 + k0 + c8;
        #pragma unroll
        for (int j = 0; j < 2; ++j)
            gl_lds16(cg + (size_t)j * 8 * 1024, &cs[bi][(wv * 2 + j) * 512]);
        // ws: 64 rows, 8 issues = 1/wave
        gl_lds16(Wot + (size_t)(n0 + wv * 8 + l8) * 1024 + k0 + c8,
                 &ws[bi][wv * 512]);
    };

    stage(0, 0);
    __syncthreads();

    for (int kt = 0; kt < 16; ++kt) {
        const int cur = kt & 1;
        if (kt < 15) stage(cur ^ 1, (kt + 1) * 64);

        const unsigned short* csc = cs[cur];
        const unsigned short* wsc = ws[cur];
        #pragma unroll
        for (int kh = 0; kh < 2; ++kh) {
            const int csw = ((kh * 4 + quad) ^ x7) * 8;
            const bf16x8 a0 = *(const bf16x8*)&csc[(wm * 32 + l15) * 64 + csw];
            const bf16x8 a1 = *(const bf16x8*)&csc[(wm * 32 + 16 + l15) * 64 + csw];
            #pragma unroll
            for (int nbh = 0; nbh < 2; ++nbh) {
                const int nb = wn * 2 + nbh;
                const bf16x8 bfr = *(const bf16x8*)&wsc[(nb * 16 + l15) * 64 + csw];
                acc[0][nbh] = __builtin_amdgcn_mfma_f32_16x16x32_bf16(a0, bfr, acc[0][nbh], 0, 0, 0);
                acc[1][nbh] = __builtin_amdgcn_mfma_f32_16x16x32_bf16(a1, bfr, acc[1][nbh], 0, 0, 0);
            }
        }
        __syncthreads();
    }

    #pragma unroll
    for (int mf = 0; mf < 2; ++mf)
        #pragma unroll
        for (int r = 0; r < 4; ++r) {
            const int m = m0 + wm * 32 + mf * 16 + quad * 4 + r;
            #pragma unroll
            for (int nbh = 0; nbh < 2; ++nbh) {
                const int nb = wn * 2 + nbh;
                out[(size_t)m * 1024 + n0 + nb * 16 + l15] = acc[mf][nbh][r];
            }
        }
}

// ===========================================================================
// FALLBACK (32 MB ws): fp32 VALU projections (R5-verified)
// ===========================================================================
__global__ __launch_bounds__(256) void qkv_proj(
    const float* __restrict__ x, const float* __restrict__ Wq,
    const float* __restrict__ Wk, const float* __restrict__ Wv,
    unsigned short* __restrict__ Qo, unsigned short* __restrict__ Ko,
    unsigned short* __restrict__ Vo)
{
    __shared__ float xs[32][68];
    __shared__ float wqs[32][68];
    __shared__ float wks[32][68];
    __shared__ float wvs[32][68];

    const int h  = blockIdx.x;
    const int m0 = blockIdx.y * 64;
    const int t  = threadIdx.x;
    const int tx = t & 15, ty = t >> 4;
    const int xr = t >> 2, xc = (t & 3) * 8;
    const int wr = t >> 3, wc = (t & 7) * 8;

    float aq[4][4] = {}, ak[4][4] = {}, av[4][4] = {};
    const int wbase = h * D_ * K_;

    for (int d0 = 0; d0 < D_; d0 += 32) {
        __syncthreads();
        {
            const float* xf = x + (size_t)(m0 + xr) * D_ + d0 + xc;
            const float4 a = *(const float4*)xf;
            const float4 b = *(const float4*)(xf + 4);
            xs[xc + 0][xr] = a.x; xs[xc + 1][xr] = a.y;
            xs[xc + 2][xr] = a.z; xs[xc + 3][xr] = a.w;
            xs[xc + 4][xr] = b.x; xs[xc + 5][xr] = b.y;
            xs[xc + 6][xr] = b.z; xs[xc + 7][xr] = b.w;
        }
        {
            const size_t idx = (size_t)wbase + (size_t)(d0 + wr) * K_ + wc;
            *(float4*)&wqs[wr][wc]     = *(const float4*)&Wq[idx];
            *(float4*)&wqs[wr][wc + 4] = *(const float4*)&Wq[idx + 4];
            *(float4*)&wks[wr][wc]     = *(const float4*)&Wk[idx];
            *(float4*)&wks[wr][wc + 4] = *(const float4*)&Wk[idx + 4];
            *(float4*)&wvs[wr][wc]     = *(const float4*)&Wv[idx];
            *(float4*)&wvs[wr][wc + 4] = *(const float4*)&Wv[idx + 4];
        }
        __syncthreads();

        #pragma unroll 8
        for (int kk = 0; kk < 32; ++kk) {
            const float4 xv = *(const float4*)&xs[kk][ty * 4];
            const float4 q4 = *(const float4*)&wqs[kk][tx * 4];
            const float4 k4 = *(const float4*)&wks[kk][tx * 4];
            const float4 v4 = *(const float4*)&wvs[kk][tx * 4];
            const float xa[4] = {xv.x, xv.y, xv.z, xv.w};
            const float qa[4] = {q4.x, q4.y, q4.z, q4.w};
            const float ka[4] = {k4.x, k4.y, k4.z, k4.w};
            const float va[4] = {v4.x, v4.y, v4.z, v4.w};
            #pragma unroll
            for (int i = 0; i < 4; ++i)
                #pragma unroll
                for (int j = 0; j < 4; ++j) {
                    aq[i][j] += xa[i] * qa[j];
                    ak[i][j] += xa[i] * ka[j];
                    av[i][j] += xa[i] * va[j];
                }
        }
    }

    #pragma unroll
    for (int i = 0; i < 4; ++i) {
        const int m  = m0 + ty * 4 + i;
        const int bb = m >> 11;
        const int ss = m & (S_ - 1);
        const size_t base = (((size_t)(bb * H_ + h)) * S_ + ss) * K_ + tx * 4;
        ushort4 pq, pk, pv;
        pq.x = f2b(aq[i][0]); pq.y = f2b(aq[i][1]); pq.z = f2b(aq[i][2]); pq.w = f2b(aq[i][3]);
        pk.x = f2b(ak[i][0]); pk.y = f2b(ak[i][1]); pk.z = f2b(ak[i][2]); pk.w = f2b(ak[i][3]);
        pv.x = f2b(av[i][0]); pv.y = f2b(av[i][1]); pv.z = f2b(av[i][2]); pv.w = f2b(av[i][3]);
        *(ushort4*)&Qo[base] = pq;
        *(ushort4*)&Ko[base] = pk;
        *(ushort4*)&Vo[base] = pv;
    }
}

__global__ __launch_bounds__(256) void out_proj(
    const unsigned int* __restrict__ Cb, const float* __restrict__ Wo,
    float* __restrict__ out)
{
    __shared__ float cs[32][68];
    __shared__ float wos[32][68];

    const int n0 = blockIdx.x * 64;
    const int m0 = blockIdx.y * 64;
    const int t  = threadIdx.x;
    const int tx = t & 15, ty = t >> 4;
    const int xr = t >> 2, xc = (t & 3) * 8;
    const int wr = t >> 3, wc = (t & 7) * 8;

    float acc[4][4] = {};

    for (int k0 = 0; k0 < 1024; k0 += 32) {
        __syncthreads();
        {
            uint4 u = *(const uint4*)&Cb[((size_t)(m0 + xr) * 1024 + k0 + xc) >> 1];
            cs[xc + 0][xr] = bf_lo(u.x); cs[xc + 1][xr] = bf_hi(u.x);
            cs[xc + 2][xr] = bf_lo(u.y); cs[xc + 3][xr] = bf_hi(u.y);
            cs[xc + 4][xr] = bf_lo(u.z); cs[xc + 5][xr] = bf_hi(u.z);
            cs[xc + 6][xr] = bf_lo(u.w); cs[xc + 7][xr] = bf_hi(u.w);
        }
        {
            const float* wof = Wo + (size_t)(k0 + wr) * 1024 + n0 + wc;
            *(float4*)&wos[wr][wc]     = *(const float4*)wof;
            *(float4*)&wos[wr][wc + 4] = *(const float4*)(wof + 4);
        }
        __syncthreads();

        #pragma unroll 8
        for (int kk = 0; kk < 32; ++kk) {
            const float4 cv = *(const float4*)&cs[kk][ty * 4];
            const float4 wv = *(const float4*)&wos[kk][tx * 4];
            const float ca[4] = {cv.x, cv.y, cv.z, cv.w};
            const float wa[4] = {wv.x, wv.y, wv.z, wv.w};
            #pragma unroll
            for (int i = 0; i < 4; ++i)
                #pragma unroll
                for (int j = 0; j < 4; ++j)
                    acc[i][j] += ca[i] * wa[j];
        }
    }

    #pragma unroll
    for (int i = 0; i < 4; ++i) {
        const int m = m0 + ty * 4 + i;
        float4 p = make_float4(acc[i][0], acc[i][1], acc[i][2], acc[i][3]);
        *(float4*)&out[(size_t)m * 1024 + n0 + tx * 4] = p;
    }
}

// ===========================================================================
extern "C" void kernel_launch(void* const* d_in, const int* in_sizes, int n_in,
                              void* d_out, int out_size, void* d_ws, size_t ws_size,
                              hipStream_t stream)
{
    (void)in_sizes; (void)n_in; (void)out_size;
    const float* x  = (const float*)d_in[0];
    const float* Wq = (const float*)d_in[1];
    const float* Wk = (const float*)d_in[2];
    const float* Wv = (const float*)d_in[3];
    const float* Wo = (const float*)d_in[4];
    float* out = (float*)d_out;

    const size_t QKV_ELEMS = (size_t)B_ * H_ * S_ * K_;   // 4,194,304

    if (ws_size >= (size_t)40 * 1024 * 1024) {
        // ws layout (bf16 elems), exactly 40 MB:
        //  xb (8MB; aliased by ctx after gemm_qkv) | Wtq|Wtk|Wtv (2MB each,
        //  CONTIGUOUS = one [3072][1024] concat matrix) | Wot (2MB) |
        //  Q (8MB) | K (8MB) | Vt (8MB, [B][H][K][S] permuted)
        unsigned short* xb  = (unsigned short*)d_ws;
        unsigned short* Wtq = xb  + (size_t)4096 * 1024;
        unsigned short* Wtk = Wtq + (size_t)16 * 64 * 1024;
        unsigned short* Wtv = Wtk + (size_t)16 * 64 * 1024;
        unsigned short* Wot = Wtv + (size_t)16 * 64 * 1024;
        unsigned short* Qb  = Wot + (size_t)1024 * 1024;
        unsigned short* Kb  = Qb + QKV_ELEMS;
        unsigned short* Vtb = Kb + QKV_ELEMS;
        unsigned short* Cb  = xb;   // alias: xb dead after gemm_qkv

        prep_all<<<dim3(5120), 256, 0, stream>>>(
            x, Wq, Wk, Wv, Wo, xb, Wtq, Wtk, Wtv, Wot);

        gemm_qkv<<<dim3(24, 32), 256, 0, stream>>>(xb, Wtq, Wtk, Wtv, Qb, Kb, Vtb);
        attn_mfma2<<<dim3(512), 256, 0, stream>>>(Qb, Kb, Vtb, Cb);
        gemm_out<<<dim3(16, 32), 512, 0, stream>>>(Cb, Wot, out);
    } else {
        // fallback (32 MB): Q | K | V | ctx   (R5-verified path)
        unsigned short* Qb = (unsigned short*)d_ws;
        unsigned short* Kb = Qb + QKV_ELEMS;
        unsigned short* Vb = Kb + QKV_ELEMS;
        unsigned short* Cb = Vb + QKV_ELEMS;

        qkv_proj<<<dim3(16, 64), 256, 0, stream>>>(x, Wq, Wk, Wv, Qb, Kb, Vb);
        attn_mfma_v1<<<dim3(32, 16, 2), 256, 0, stream>>>(Qb, Kb, Vb, Cb);
        out_proj<<<dim3(16, 64), 256, 0, stream>>>((const unsigned int*)Cb, Wo, out);
    }
}